// Round 7
// baseline (1509.173 us; speedup 1.0000x reference)
//
#include <hip/hip_runtime.h>
#include <hip/hip_fp16.h>

#define HF 96
#define C4 24          // float4 chunks per f32 row
#define CH 12          // uint4 (8-half) chunks per f16 row
#define NGRAPHS 500
#define EPS 1e-5f

__device__ __forceinline__ float4 h4tof4(uint2 u) {
    __half2 a = *(__half2*)&u.x;
    __half2 b = *(__half2*)&u.y;
    float2 fa = __half22float2(a);
    float2 fb = __half22float2(b);
    return make_float4(fa.x, fa.y, fb.x, fb.y);
}

// ---------------- CSR build ----------------

__global__ void count_kernel(const int* __restrict__ dst, int E, int* __restrict__ cnt) {
    int stride = gridDim.x * blockDim.x;
    for (int i = blockIdx.x * blockDim.x + threadIdx.x; i < E; i += stride)
        atomicAdd(&cnt[dst[i]], 1);
}

__global__ void node_init_kernel(const int* __restrict__ cnt, int N,
                                 float* __restrict__ dinv, float* __restrict__ selfw) {
    int stride = gridDim.x * blockDim.x;
    for (int i = blockIdx.x * blockDim.x + threadIdx.x; i < N; i += stride) {
        float d = (float)(cnt[i] + 1);      // +1 self loop
        dinv[i] = 1.0f / sqrtf(d);
        selfw[i] = 1.0f / d;
    }
}

__global__ void scan1_kernel(const int* __restrict__ cnt, int N, int* __restrict__ bsum) {
    __shared__ int s[256];
    int t = threadIdx.x;
    int i = blockIdx.x * 256 + t;
    s[t] = (i < N) ? cnt[i] : 0;
    __syncthreads();
    for (int off = 128; off; off >>= 1) {
        if (t < off) s[t] += s[t + off];
        __syncthreads();
    }
    if (t == 0) bsum[blockIdx.x] = s[0];
}

__global__ void scan2_kernel(const int* __restrict__ bsum, int NB,
                             int* __restrict__ boff, int* __restrict__ row_ptr, int N) {
    __shared__ int s[256];
    int t = threadIdx.x;
    int v = (t < NB) ? bsum[t] : 0;
    s[t] = v;
    __syncthreads();
    for (int off = 1; off < 256; off <<= 1) {
        int u = (t >= off) ? s[t - off] : 0;
        __syncthreads();
        s[t] += u;
        __syncthreads();
    }
    if (t < NB) boff[t] = s[t] - v;
    if (t == 255) row_ptr[N] = s[255];
}

__global__ void scan3_kernel(int* __restrict__ cnt, int N, const int* __restrict__ boff,
                             int* __restrict__ row_ptr) {
    __shared__ int s[256];
    int t = threadIdx.x;
    int i = blockIdx.x * 256 + t;
    int v = (i < N) ? cnt[i] : 0;
    s[t] = v;
    __syncthreads();
    for (int off = 1; off < 256; off <<= 1) {
        int u = (t >= off) ? s[t - off] : 0;
        __syncthreads();
        s[t] += u;
        __syncthreads();
    }
    if (i < N) {
        row_ptr[i] = boff[blockIdx.x] + s[t] - v;
        cnt[i] = 0;
    }
}

__global__ void scatter_kernel(const int* __restrict__ src, const int* __restrict__ dst, int E,
                               const int* __restrict__ row_ptr, int* __restrict__ cnt,
                               const float* __restrict__ dinv,
                               int2* __restrict__ csr) {
    int stride = gridDim.x * blockDim.x;
    for (int i = blockIdx.x * blockDim.x + threadIdx.x; i < E; i += stride) {
        int d = dst[i], s = src[i];
        int p = row_ptr[d] + atomicAdd(&cnt[d], 1);
        float w = dinv[s] * dinv[d];
        csr[p] = make_int2(s, __float_as_int(w));
    }
}

// ---------------- per-layer: matmul (fused BN+ReLU of prev layer), f16 output ----------------

__global__ __launch_bounds__(256) void
matmul_kernel(const float* __restrict__ in, const float* __restrict__ W,
              __half* __restrict__ out, int N, int applyBN,
              const double* __restrict__ bnsum,
              const float* __restrict__ bnG, const float* __restrict__ bnB) {
    __shared__ float4 sW[HF * C4];           // 36 KB: W[k][4c..4c+3]
    __shared__ float4 sAl[C4], sBe[C4];
    for (int i = threadIdx.x; i < HF * C4; i += blockDim.x)
        sW[i] = ((const float4*)W)[i];
    if (threadIdx.x < HF) {
        float a = 1.f, b = 0.f;
        if (applyBN) {
            double invN = 1.0 / (double)N;
            double mu = bnsum[threadIdx.x] * invN;
            double var = bnsum[HF + threadIdx.x] * invN - mu * mu;
            float v = fmaxf((float)var, 0.f) + EPS;
            a = bnG[threadIdx.x] / sqrtf(v);
            b = bnB[threadIdx.x] - (float)mu * a;
        }
        ((float*)sAl)[threadIdx.x] = a;
        ((float*)sBe)[threadIdx.x] = b;
    }
    __syncthreads();
    int nG = (N + 3) >> 2;                   // 4-node register tile
    int total = nG * C4;
    int stride = gridDim.x * blockDim.x;
    for (int idx = blockIdx.x * blockDim.x + threadIdx.x; idx < total; idx += stride) {
        int ng = idx / C4, c = idx % C4;
        int n0 = ng * 4;
        int rem = N - n0;                    // >=1
        const float4* r0 = (const float4*)(in + (size_t)n0 * HF);
        const float4* r1 = r0 + ((rem > 1) ? C4 : 0);
        const float4* r2 = r0 + ((rem > 2) ? 2 * C4 : 0);
        const float4* r3 = r0 + ((rem > 3) ? 3 * C4 : 0);
        float4 acc0 = make_float4(0.f, 0.f, 0.f, 0.f);
        float4 acc1 = acc0, acc2 = acc0, acc3 = acc0;
#pragma unroll 4
        for (int k4 = 0; k4 < C4; ++k4) {
            float4 al = sAl[k4], be = sBe[k4];
            float4 w0 = sW[(k4 * 4 + 0) * C4 + c];
            float4 w1 = sW[(k4 * 4 + 1) * C4 + c];
            float4 w2 = sW[(k4 * 4 + 2) * C4 + c];
            float4 w3 = sW[(k4 * 4 + 3) * C4 + c];
            float4 a0 = r0[k4], a1 = r1[k4], a2 = r2[k4], a3 = r3[k4];
            if (applyBN) {
                a0.x = fmaxf(fmaf(a0.x, al.x, be.x), 0.f); a0.y = fmaxf(fmaf(a0.y, al.y, be.y), 0.f);
                a0.z = fmaxf(fmaf(a0.z, al.z, be.z), 0.f); a0.w = fmaxf(fmaf(a0.w, al.w, be.w), 0.f);
                a1.x = fmaxf(fmaf(a1.x, al.x, be.x), 0.f); a1.y = fmaxf(fmaf(a1.y, al.y, be.y), 0.f);
                a1.z = fmaxf(fmaf(a1.z, al.z, be.z), 0.f); a1.w = fmaxf(fmaf(a1.w, al.w, be.w), 0.f);
                a2.x = fmaxf(fmaf(a2.x, al.x, be.x), 0.f); a2.y = fmaxf(fmaf(a2.y, al.y, be.y), 0.f);
                a2.z = fmaxf(fmaf(a2.z, al.z, be.z), 0.f); a2.w = fmaxf(fmaf(a2.w, al.w, be.w), 0.f);
                a3.x = fmaxf(fmaf(a3.x, al.x, be.x), 0.f); a3.y = fmaxf(fmaf(a3.y, al.y, be.y), 0.f);
                a3.z = fmaxf(fmaf(a3.z, al.z, be.z), 0.f); a3.w = fmaxf(fmaf(a3.w, al.w, be.w), 0.f);
            }
#define ACC(ACCV, AV) \
            ACCV.x = fmaf(AV.x, w0.x, fmaf(AV.y, w1.x, fmaf(AV.z, w2.x, fmaf(AV.w, w3.x, ACCV.x)))); \
            ACCV.y = fmaf(AV.x, w0.y, fmaf(AV.y, w1.y, fmaf(AV.z, w2.y, fmaf(AV.w, w3.y, ACCV.y)))); \
            ACCV.z = fmaf(AV.x, w0.z, fmaf(AV.y, w1.z, fmaf(AV.z, w2.z, fmaf(AV.w, w3.z, ACCV.z)))); \
            ACCV.w = fmaf(AV.x, w0.w, fmaf(AV.y, w1.w, fmaf(AV.z, w2.w, fmaf(AV.w, w3.w, ACCV.w))));
            ACC(acc0, a0) ACC(acc1, a1) ACC(acc2, a2) ACC(acc3, a3)
#undef ACC
        }
        uint2* orow = (uint2*)out;
#define STORE(J, ACCV) \
        if (rem > J) { \
            __half2 lo = __floats2half2_rn(ACCV.x, ACCV.y); \
            __half2 hi = __floats2half2_rn(ACCV.z, ACCV.w); \
            orow[(size_t)(n0 + J) * C4 + c] = make_uint2(*(unsigned int*)&lo, *(unsigned int*)&hi); \
        }
        STORE(0, acc0) STORE(1, acc1) STORE(2, acc2) STORE(3, acc3)
#undef STORE
    }
}

// ---------------- per-layer: edge aggregation, 4-lane edge-sliced, f16 gathers ----------------

__global__ __launch_bounds__(256, 4) void
agg_kernel(const __half* __restrict__ Hb, float* __restrict__ out,
           const int* __restrict__ row_ptr, const int2* __restrict__ csr,
           const float* __restrict__ selfw, const float* __restrict__ convB,
           int N, double* __restrict__ bnsum) {
    __shared__ float sred[2 * HF];
    bool stats = (bnsum != nullptr);
    for (int i = threadIdx.x; i < 2 * HF; i += blockDim.x) sred[i] = 0.f;
    __syncthreads();
    const uint4* h4p = (const uint4*)Hb;     // row = CH uint4 chunks of 8 halfs
    int total = N * CH * 4;                  // (node, chunk, slice)
    int stride = gridDim.x * blockDim.x;     // multiple of 4
    for (int idx = blockIdx.x * blockDim.x + threadIdx.x; idx < total; idx += stride) {
        int n = idx / (CH * 4);
        int r = idx % (CH * 4);
        int c = r >> 2;
        int s = r & 3;                       // edge slice: lanes 4k..4k+3 share (n,c)
        const uint4* hp = h4p + c;
        int p0 = row_ptr[n], p1 = row_ptr[n + 1];
        float4 alo = make_float4(0.f, 0.f, 0.f, 0.f);
        float4 ahi = alo;
        if (s == 0) {                        // self-loop + bias on slice 0 only
            float sw = selfw[n];
            uint4 hraw = hp[(size_t)n * CH];
            float4 hlo = h4tof4(make_uint2(hraw.x, hraw.y));
            float4 hhi = h4tof4(make_uint2(hraw.z, hraw.w));
            float4 blo = ((const float4*)convB)[2 * c];
            float4 bhi = ((const float4*)convB)[2 * c + 1];
            alo.x = fmaf(sw, hlo.x, blo.x); alo.y = fmaf(sw, hlo.y, blo.y);
            alo.z = fmaf(sw, hlo.z, blo.z); alo.w = fmaf(sw, hlo.w, blo.w);
            ahi.x = fmaf(sw, hhi.x, bhi.x); ahi.y = fmaf(sw, hhi.y, bhi.y);
            ahi.z = fmaf(sw, hhi.z, bhi.z); ahi.w = fmaf(sw, hhi.w, bhi.w);
        }
#define EDGE(EV, RV) { \
            float w = __int_as_float(EV.y); \
            float4 vlo = h4tof4(make_uint2(RV.x, RV.y)); \
            float4 vhi = h4tof4(make_uint2(RV.z, RV.w)); \
            alo.x = fmaf(w, vlo.x, alo.x); alo.y = fmaf(w, vlo.y, alo.y); \
            alo.z = fmaf(w, vlo.z, alo.z); alo.w = fmaf(w, vlo.w, alo.w); \
            ahi.x = fmaf(w, vhi.x, ahi.x); ahi.y = fmaf(w, vhi.y, ahi.y); \
            ahi.z = fmaf(w, vhi.z, ahi.z); ahi.w = fmaf(w, vhi.w, ahi.w); }
        int p = p0 + s;
        for (; p + 12 < p1; p += 16) {       // 4-deep within this slice
            int2 e0 = csr[p], e1 = csr[p + 4], e2 = csr[p + 8], e3 = csr[p + 12];
            uint4 g0 = hp[(size_t)e0.x * CH];
            uint4 g1 = hp[(size_t)e1.x * CH];
            uint4 g2 = hp[(size_t)e2.x * CH];
            uint4 g3 = hp[(size_t)e3.x * CH];
            EDGE(e0, g0) EDGE(e1, g1) EDGE(e2, g2) EDGE(e3, g3)
        }
        for (; p < p1; p += 4) {
            int2 e = csr[p];
            uint4 g = hp[(size_t)e.x * CH];
            EDGE(e, g)
        }
#undef EDGE
        // combine 4 slices (lanes differing in bits 0-1 of lane id)
        for (int m = 1; m <= 2; m <<= 1) {
            alo.x += __shfl_xor(alo.x, m); alo.y += __shfl_xor(alo.y, m);
            alo.z += __shfl_xor(alo.z, m); alo.w += __shfl_xor(alo.w, m);
            ahi.x += __shfl_xor(ahi.x, m); ahi.y += __shfl_xor(ahi.y, m);
            ahi.z += __shfl_xor(ahi.z, m); ahi.w += __shfl_xor(ahi.w, m);
        }
        if (s == 0) {
            int o = n * CH + c;
            ((float4*)out)[2 * o]     = alo;
            ((float4*)out)[2 * o + 1] = ahi;
            if (stats) {
                int f = 8 * c;
                atomicAdd(&sred[f + 0], alo.x); atomicAdd(&sred[f + 1], alo.y);
                atomicAdd(&sred[f + 2], alo.z); atomicAdd(&sred[f + 3], alo.w);
                atomicAdd(&sred[f + 4], ahi.x); atomicAdd(&sred[f + 5], ahi.y);
                atomicAdd(&sred[f + 6], ahi.z); atomicAdd(&sred[f + 7], ahi.w);
                atomicAdd(&sred[HF + f + 0], alo.x * alo.x); atomicAdd(&sred[HF + f + 1], alo.y * alo.y);
                atomicAdd(&sred[HF + f + 2], alo.z * alo.z); atomicAdd(&sred[HF + f + 3], alo.w * alo.w);
                atomicAdd(&sred[HF + f + 4], ahi.x * ahi.x); atomicAdd(&sred[HF + f + 5], ahi.y * ahi.y);
                atomicAdd(&sred[HF + f + 6], ahi.z * ahi.z); atomicAdd(&sred[HF + f + 7], ahi.w * ahi.w);
            }
        }
    }
    if (stats) {
        __syncthreads();
        for (int i = threadIdx.x; i < 2 * HF; i += blockDim.x)
            atomicAdd(&bnsum[i], (double)sred[i]);
    }
}

// ---------------- pooling + head (fused) ----------------

__global__ __launch_bounds__(128) void
pool_head1_kernel(const float* __restrict__ xin, const int* __restrict__ batch, int N,
                  const float* __restrict__ W1, const float* __restrict__ b1,
                  float* __restrict__ tmp1, double* __restrict__ bnsum) {
    __shared__ float row[HF];
    int g = blockIdx.x;
    int lo = 0, hi = N;
    while (lo < hi) { int m = (lo + hi) >> 1; if (batch[m] < g) lo = m + 1; else hi = m; }
    int s0 = lo;
    lo = s0; hi = N;
    while (lo < hi) { int m = (lo + hi) >> 1; if (batch[m] < g + 1) lo = m + 1; else hi = m; }
    int s1 = lo;
    int f = threadIdx.x;
    if (f < HF) {
        float sum = 0.f;
        for (int n = s0; n < s1; ++n) sum += xin[(size_t)n * HF + f];
        float inv = 1.0f / fmaxf((float)(s1 - s0), 1.0f);
        row[f] = sum * inv;
    }
    __syncthreads();
    if (f < HF) {
        float acc = b1[f];
        for (int k = 0; k < HF; ++k) acc = fmaf(row[k], W1[k * HF + f], acc);
        tmp1[g * HF + f] = acc;
        atomicAdd(&bnsum[f], (double)acc);
        atomicAdd(&bnsum[HF + f], (double)(acc * acc));
    }
}

__global__ __launch_bounds__(128) void
head23_kernel(const float* __restrict__ tmp1, const double* __restrict__ bnsum,
              const float* __restrict__ g1, const float* __restrict__ be1,
              const float* __restrict__ W2, const float* __restrict__ b2,
              const float* __restrict__ W3, const float* __restrict__ b3,
              float* __restrict__ out) {
    __shared__ float row[HF], row2[HF];
    int g = blockIdx.x;
    int f = threadIdx.x;
    if (f < HF) {
        double mu = bnsum[f] / (double)NGRAPHS;
        double var = bnsum[HF + f] / (double)NGRAPHS - mu * mu;
        float v = fmaxf((float)var, 0.f) + EPS;
        float a = g1[f] / sqrtf(v);
        float bb = be1[f] - (float)mu * a;
        row[f] = fmaxf(fmaf(tmp1[g * HF + f], a, bb), 0.f);
    }
    __syncthreads();
    if (f < HF) {
        float acc = b2[f];
        for (int k = 0; k < HF; ++k) acc = fmaf(row[k], W2[k * HF + f], acc);
        row2[f] = fmaxf(acc, 0.f);
    }
    __syncthreads();
    if (f < 10) {
        float acc = b3[f];
        for (int k = 0; k < HF; ++k) acc = fmaf(row2[k], W3[k * 10 + f], acc);
        out[g * 10 + f] = acc;
    }
}

// ---------------- launch ----------------

extern "C" void kernel_launch(void* const* d_in, const int* in_sizes, int n_in,
                              void* d_out, int out_size, void* d_ws, size_t ws_size,
                              hipStream_t stream) {
    (void)n_in; (void)out_size; (void)ws_size;
    const float* x     = (const float*)d_in[0];
    const int*   ei    = (const int*)d_in[1];
    const int*   batch = (const int*)d_in[2];
    const float* convW = (const float*)d_in[3];
    const float* convB = (const float*)d_in[4];
    const float* bnG   = (const float*)d_in[5];
    const float* bnB   = (const float*)d_in[6];
    const float* W1    = (const float*)d_in[7];
    const float* b1    = (const float*)d_in[8];
    const float* g1    = (const float*)d_in[9];
    const float* be1   = (const float*)d_in[10];
    const float* W2    = (const float*)d_in[11];
    const float* b2    = (const float*)d_in[12];
    const float* W3    = (const float*)d_in[13];
    const float* b3    = (const float*)d_in[14];
    float* outp = (float*)d_out;

    int N = in_sizes[0] / HF;
    int E = in_sizes[1] / 2;
    int NB = (N + 255) / 256;
    const int* src  = ei;
    const int* dstp = ei + E;

    char* ws = (char*)d_ws;
    size_t off = 0;
    auto alloc = [&](size_t bytes) -> char* {
        char* p = ws + off;
        off += (bytes + 255) & ~(size_t)255;
        return p;
    };
    __half* Hb     = (__half*)alloc((size_t)N * HF * 2);
    float* Ob      = (float*)alloc((size_t)N * HF * 4);
    int2*  csr     = (int2*)alloc((size_t)E * 8);
    int*   row_ptr = (int*)alloc((size_t)(N + 1) * 4);
    float* dinv    = (float*)alloc((size_t)N * 4);
    float* selfw   = (float*)alloc((size_t)N * 4);
    int*   bsum    = (int*)alloc((size_t)NB * 4);
    int*   boff    = (int*)alloc((size_t)NB * 4);
    float* tmp1    = (float*)alloc((size_t)NGRAPHS * HF * 4);
    char* zstart   = ws + off;
    int*    cnt    = (int*)alloc((size_t)N * 4);
    double* bns    = (double*)alloc(6 * 2 * HF * 8);   // 5 conv BN + 1 head BN
    size_t zbytes  = (size_t)((ws + off) - zstart);

    hipMemsetAsync(zstart, 0, zbytes, stream);

    count_kernel<<<1024, 256, 0, stream>>>(dstp, E, cnt);
    node_init_kernel<<<(N + 255) / 256, 256, 0, stream>>>(cnt, N, dinv, selfw);
    scan1_kernel<<<NB, 256, 0, stream>>>(cnt, N, bsum);
    scan2_kernel<<<1, 256, 0, stream>>>(bsum, NB, boff, row_ptr, N);
    scan3_kernel<<<NB, 256, 0, stream>>>(cnt, N, boff, row_ptr);
    scatter_kernel<<<1024, 256, 0, stream>>>(src, dstp, E, row_ptr, cnt, dinv, csr);

    int agg_grid = (N * CH * 4 + 255) / 256;   // one (node,chunk,slice) per thread
    const float* cur = x;
    for (int i = 0; i < 6; ++i) {
        int nG = (N + 3) >> 2;
        int mm_grid = (nG * C4 + 255) / 256;
        matmul_kernel<<<mm_grid, 256, 0, stream>>>(
            cur, convW + (size_t)i * HF * HF, Hb, N,
            (i > 0) ? 1 : 0,
            (i > 0) ? bns + (size_t)(i - 1) * 2 * HF : nullptr,
            (i > 0) ? bnG + (size_t)(i - 1) * HF : nullptr,
            (i > 0) ? bnB + (size_t)(i - 1) * HF : nullptr);
        agg_kernel<<<agg_grid, 256, 0, stream>>>(
            Hb, Ob, row_ptr, csr, selfw,
            convB + (size_t)i * HF, N,
            (i < 5) ? bns + (size_t)i * 2 * HF : nullptr);
        cur = Ob;
    }

    pool_head1_kernel<<<NGRAPHS, 128, 0, stream>>>(Ob, batch, N, W1, b1, tmp1, bns + 5 * 2 * HF);
    head23_kernel<<<NGRAPHS, 128, 0, stream>>>(tmp1, bns + 5 * 2 * HF, g1, be1, W2, b2, W3, b3, outp);
}

// Round 9
// 1077.194 us; speedup vs baseline: 1.4010x; 1.4010x over previous
//
#include <hip/hip_runtime.h>
#include <hip/hip_fp16.h>

#define HF 96
#define C4 24          // float4 chunks per f32 row
#define CH 12          // uint4 (8-half) chunks per f16 row
#define NPASS 3        // column passes over the f16 table
#define CPP 4          // chunks per pass (4*16B = 64B = 1 cache line per row)
#define NGRAPHS 500
#define EPS 1e-5f

__device__ __forceinline__ float4 h4tof4(uint2 u) {
    __half2 a = *(__half2*)&u.x;
    __half2 b = *(__half2*)&u.y;
    float2 fa = __half22float2(a);
    float2 fb = __half22float2(b);
    return make_float4(fa.x, fa.y, fb.x, fb.y);
}

// nontemporal helpers (keep streaming data out of L2 so the gather slice stays resident)
__device__ __forceinline__ int2 ld_nt_int2(const int2* p) {
    typedef int i2 __attribute__((ext_vector_type(2)));
    i2 v = __builtin_nontemporal_load((const i2*)p);
    return make_int2(v.x, v.y);
}
__device__ __forceinline__ void st_nt_f4(float* p, float4 v) {
    typedef float f4 __attribute__((ext_vector_type(4)));
    f4 t; t.x = v.x; t.y = v.y; t.z = v.z; t.w = v.w;
    __builtin_nontemporal_store(t, (f4*)p);
}

// ---------------- CSR build ----------------

__global__ void count_kernel(const int* __restrict__ dst, int E, int* __restrict__ cnt) {
    int stride = gridDim.x * blockDim.x;
    for (int i = blockIdx.x * blockDim.x + threadIdx.x; i < E; i += stride)
        atomicAdd(&cnt[dst[i]], 1);
}

__global__ void node_init_kernel(const int* __restrict__ cnt, int N,
                                 float* __restrict__ dinv, float* __restrict__ selfw) {
    int stride = gridDim.x * blockDim.x;
    for (int i = blockIdx.x * blockDim.x + threadIdx.x; i < N; i += stride) {
        float d = (float)(cnt[i] + 1);      // +1 self loop
        dinv[i] = 1.0f / sqrtf(d);
        selfw[i] = 1.0f / d;
    }
}

__global__ void scan1_kernel(const int* __restrict__ cnt, int N, int* __restrict__ bsum) {
    __shared__ int s[256];
    int t = threadIdx.x;
    int i = blockIdx.x * 256 + t;
    s[t] = (i < N) ? cnt[i] : 0;
    __syncthreads();
    for (int off = 128; off; off >>= 1) {
        if (t < off) s[t] += s[t + off];
        __syncthreads();
    }
    if (t == 0) bsum[blockIdx.x] = s[0];
}

__global__ void scan2_kernel(const int* __restrict__ bsum, int NB,
                             int* __restrict__ boff, int* __restrict__ row_ptr, int N) {
    __shared__ int s[256];
    int t = threadIdx.x;
    int v = (t < NB) ? bsum[t] : 0;
    s[t] = v;
    __syncthreads();
    for (int off = 1; off < 256; off <<= 1) {
        int u = (t >= off) ? s[t - off] : 0;
        __syncthreads();
        s[t] += u;
        __syncthreads();
    }
    if (t < NB) boff[t] = s[t] - v;
    if (t == 255) row_ptr[N] = s[255];
}

__global__ void scan3_kernel(int* __restrict__ cnt, int N, const int* __restrict__ boff,
                             int* __restrict__ row_ptr) {
    __shared__ int s[256];
    int t = threadIdx.x;
    int i = blockIdx.x * 256 + t;
    int v = (i < N) ? cnt[i] : 0;
    s[t] = v;
    __syncthreads();
    for (int off = 1; off < 256; off <<= 1) {
        int u = (t >= off) ? s[t - off] : 0;
        __syncthreads();
        s[t] += u;
        __syncthreads();
    }
    if (i < N) {
        row_ptr[i] = boff[blockIdx.x] + s[t] - v;
        cnt[i] = 0;
    }
}

__global__ void scatter_kernel(const int* __restrict__ src, const int* __restrict__ dst, int E,
                               const int* __restrict__ row_ptr, int* __restrict__ cnt,
                               const float* __restrict__ dinv,
                               int2* __restrict__ csr) {
    int stride = gridDim.x * blockDim.x;
    for (int i = blockIdx.x * blockDim.x + threadIdx.x; i < E; i += stride) {
        int d = dst[i], s = src[i];
        int p = row_ptr[d] + atomicAdd(&cnt[d], 1);
        float w = dinv[s] * dinv[d];
        csr[p] = make_int2(s, __float_as_int(w));
    }
}

// ---------------- per-layer: matmul (fused BN+ReLU of prev layer), f16 output ----------------

__global__ __launch_bounds__(256) void
matmul_kernel(const float* __restrict__ in, const float* __restrict__ W,
              __half* __restrict__ out, int N, int applyBN,
              const double* __restrict__ bnsum,
              const float* __restrict__ bnG, const float* __restrict__ bnB) {
    __shared__ float4 sW[HF * C4];           // 36 KB: W[k][4c..4c+3]
    __shared__ float4 sAl[C4], sBe[C4];
    for (int i = threadIdx.x; i < HF * C4; i += blockDim.x)
        sW[i] = ((const float4*)W)[i];
    if (threadIdx.x < HF) {
        float a = 1.f, b = 0.f;
        if (applyBN) {
            double invN = 1.0 / (double)N;
            double mu = bnsum[threadIdx.x] * invN;
            double var = bnsum[HF + threadIdx.x] * invN - mu * mu;
            float v = fmaxf((float)var, 0.f) + EPS;
            a = bnG[threadIdx.x] / sqrtf(v);
            b = bnB[threadIdx.x] - (float)mu * a;
        }
        ((float*)sAl)[threadIdx.x] = a;
        ((float*)sBe)[threadIdx.x] = b;
    }
    __syncthreads();
    int nG = (N + 3) >> 2;                   // 4-node register tile
    int total = nG * C4;
    int stride = gridDim.x * blockDim.x;
    for (int idx = blockIdx.x * blockDim.x + threadIdx.x; idx < total; idx += stride) {
        int ng = idx / C4, c = idx % C4;
        int n0 = ng * 4;
        int rem = N - n0;                    // >=1
        const float4* r0 = (const float4*)(in + (size_t)n0 * HF);
        const float4* r1 = r0 + ((rem > 1) ? C4 : 0);
        const float4* r2 = r0 + ((rem > 2) ? 2 * C4 : 0);
        const float4* r3 = r0 + ((rem > 3) ? 3 * C4 : 0);
        float4 acc0 = make_float4(0.f, 0.f, 0.f, 0.f);
        float4 acc1 = acc0, acc2 = acc0, acc3 = acc0;
#pragma unroll 4
        for (int k4 = 0; k4 < C4; ++k4) {
            float4 al = sAl[k4], be = sBe[k4];
            float4 w0 = sW[(k4 * 4 + 0) * C4 + c];
            float4 w1 = sW[(k4 * 4 + 1) * C4 + c];
            float4 w2 = sW[(k4 * 4 + 2) * C4 + c];
            float4 w3 = sW[(k4 * 4 + 3) * C4 + c];
            float4 a0 = r0[k4], a1 = r1[k4], a2 = r2[k4], a3 = r3[k4];
            if (applyBN) {
                a0.x = fmaxf(fmaf(a0.x, al.x, be.x), 0.f); a0.y = fmaxf(fmaf(a0.y, al.y, be.y), 0.f);
                a0.z = fmaxf(fmaf(a0.z, al.z, be.z), 0.f); a0.w = fmaxf(fmaf(a0.w, al.w, be.w), 0.f);
                a1.x = fmaxf(fmaf(a1.x, al.x, be.x), 0.f); a1.y = fmaxf(fmaf(a1.y, al.y, be.y), 0.f);
                a1.z = fmaxf(fmaf(a1.z, al.z, be.z), 0.f); a1.w = fmaxf(fmaf(a1.w, al.w, be.w), 0.f);
                a2.x = fmaxf(fmaf(a2.x, al.x, be.x), 0.f); a2.y = fmaxf(fmaf(a2.y, al.y, be.y), 0.f);
                a2.z = fmaxf(fmaf(a2.z, al.z, be.z), 0.f); a2.w = fmaxf(fmaf(a2.w, al.w, be.w), 0.f);
                a3.x = fmaxf(fmaf(a3.x, al.x, be.x), 0.f); a3.y = fmaxf(fmaf(a3.y, al.y, be.y), 0.f);
                a3.z = fmaxf(fmaf(a3.z, al.z, be.z), 0.f); a3.w = fmaxf(fmaf(a3.w, al.w, be.w), 0.f);
            }
#define ACC(ACCV, AV) \
            ACCV.x = fmaf(AV.x, w0.x, fmaf(AV.y, w1.x, fmaf(AV.z, w2.x, fmaf(AV.w, w3.x, ACCV.x)))); \
            ACCV.y = fmaf(AV.x, w0.y, fmaf(AV.y, w1.y, fmaf(AV.z, w2.y, fmaf(AV.w, w3.y, ACCV.y)))); \
            ACCV.z = fmaf(AV.x, w0.z, fmaf(AV.y, w1.z, fmaf(AV.z, w2.z, fmaf(AV.w, w3.z, ACCV.z)))); \
            ACCV.w = fmaf(AV.x, w0.w, fmaf(AV.y, w1.w, fmaf(AV.z, w2.w, fmaf(AV.w, w3.w, ACCV.w))));
            ACC(acc0, a0) ACC(acc1, a1) ACC(acc2, a2) ACC(acc3, a3)
#undef ACC
        }
        uint2* orow = (uint2*)out;
#define STORE(J, ACCV) \
        if (rem > J) { \
            __half2 lo = __floats2half2_rn(ACCV.x, ACCV.y); \
            __half2 hi = __floats2half2_rn(ACCV.z, ACCV.w); \
            orow[(size_t)(n0 + J) * C4 + c] = make_uint2(*(unsigned int*)&lo, *(unsigned int*)&hi); \
        }
        STORE(0, acc0) STORE(1, acc1) STORE(2, acc2) STORE(3, acc3)
#undef STORE
    }
}

// ---------------- per-layer: edge aggregation, 3 column passes (64B slice L2-resident) ----------------

__global__ __launch_bounds__(256) void
agg_pass_kernel(const __half* __restrict__ Hb, float* __restrict__ out,
                const int* __restrict__ row_ptr, const int2* __restrict__ csr,
                const float* __restrict__ selfw, const float* __restrict__ convB,
                int N, int c0, double* __restrict__ bnsum) {
    __shared__ float sred[2 * HF];
    bool stats = (bnsum != nullptr);
    for (int i = threadIdx.x; i < 2 * HF; i += blockDim.x) sred[i] = 0.f;
    __syncthreads();
    const uint4* h4p = (const uint4*)Hb;     // row = CH uint4 chunks of 8 halfs
    int total = N * CPP;
    int stride = gridDim.x * blockDim.x;
    for (int idx = blockIdx.x * blockDim.x + threadIdx.x; idx < total; idx += stride) {
        int n = idx >> 2;
        int c = c0 + (idx & 3);              // 4 lanes/node cover one 64B line of the row
        const uint4* hp = h4p + c;
        int p0 = __builtin_nontemporal_load(row_ptr + n);
        int p1 = __builtin_nontemporal_load(row_ptr + n + 1);
        float sw = __builtin_nontemporal_load(selfw + n);
        uint4 hraw = hp[(size_t)n * CH];
        float4 hlo = h4tof4(make_uint2(hraw.x, hraw.y));
        float4 hhi = h4tof4(make_uint2(hraw.z, hraw.w));
        float4 blo = ((const float4*)convB)[2 * c];
        float4 bhi = ((const float4*)convB)[2 * c + 1];
        float4 alo, ahi;
        alo.x = fmaf(sw, hlo.x, blo.x); alo.y = fmaf(sw, hlo.y, blo.y);
        alo.z = fmaf(sw, hlo.z, blo.z); alo.w = fmaf(sw, hlo.w, blo.w);
        ahi.x = fmaf(sw, hhi.x, bhi.x); ahi.y = fmaf(sw, hhi.y, bhi.y);
        ahi.z = fmaf(sw, hhi.z, bhi.z); ahi.w = fmaf(sw, hhi.w, bhi.w);
#define EDGE(EV, RV) { \
            float w = __int_as_float(EV.y); \
            float4 vlo = h4tof4(make_uint2(RV.x, RV.y)); \
            float4 vhi = h4tof4(make_uint2(RV.z, RV.w)); \
            alo.x = fmaf(w, vlo.x, alo.x); alo.y = fmaf(w, vlo.y, alo.y); \
            alo.z = fmaf(w, vlo.z, alo.z); alo.w = fmaf(w, vlo.w, alo.w); \
            ahi.x = fmaf(w, vhi.x, ahi.x); ahi.y = fmaf(w, vhi.y, ahi.y); \
            ahi.z = fmaf(w, vhi.z, ahi.z); ahi.w = fmaf(w, vhi.w, ahi.w); }
        int p = p0;
        for (; p + 4 <= p1; p += 4) {
            int2 e0 = ld_nt_int2(csr + p);
            int2 e1 = ld_nt_int2(csr + p + 1);
            int2 e2 = ld_nt_int2(csr + p + 2);
            int2 e3 = ld_nt_int2(csr + p + 3);
            uint4 g0 = hp[(size_t)e0.x * CH];
            uint4 g1 = hp[(size_t)e1.x * CH];
            uint4 g2 = hp[(size_t)e2.x * CH];
            uint4 g3 = hp[(size_t)e3.x * CH];
            EDGE(e0, g0) EDGE(e1, g1) EDGE(e2, g2) EDGE(e3, g3)
        }
        for (; p < p1; ++p) {
            int2 e = ld_nt_int2(csr + p);
            uint4 g = hp[(size_t)e.x * CH];
            EDGE(e, g)
        }
#undef EDGE
        int o = n * CH + c;
        st_nt_f4(out + 8 * (size_t)o, alo);
        st_nt_f4(out + 8 * (size_t)o + 4, ahi);
        if (stats) {
            int f = 8 * c;
            atomicAdd(&sred[f + 0], alo.x); atomicAdd(&sred[f + 1], alo.y);
            atomicAdd(&sred[f + 2], alo.z); atomicAdd(&sred[f + 3], alo.w);
            atomicAdd(&sred[f + 4], ahi.x); atomicAdd(&sred[f + 5], ahi.y);
            atomicAdd(&sred[f + 6], ahi.z); atomicAdd(&sred[f + 7], ahi.w);
            atomicAdd(&sred[HF + f + 0], alo.x * alo.x); atomicAdd(&sred[HF + f + 1], alo.y * alo.y);
            atomicAdd(&sred[HF + f + 2], alo.z * alo.z); atomicAdd(&sred[HF + f + 3], alo.w * alo.w);
            atomicAdd(&sred[HF + f + 4], ahi.x * ahi.x); atomicAdd(&sred[HF + f + 5], ahi.y * ahi.y);
            atomicAdd(&sred[HF + f + 6], ahi.z * ahi.z); atomicAdd(&sred[HF + f + 7], ahi.w * ahi.w);
        }
    }
    if (stats) {
        __syncthreads();
        for (int i = threadIdx.x; i < 2 * HF; i += blockDim.x)
            atomicAdd(&bnsum[i], (double)sred[i]);
    }
}

// ---------------- pooling + head (fused) ----------------

__global__ __launch_bounds__(128) void
pool_head1_kernel(const float* __restrict__ xin, const int* __restrict__ batch, int N,
                  const float* __restrict__ W1, const float* __restrict__ b1,
                  float* __restrict__ tmp1, double* __restrict__ bnsum) {
    __shared__ float row[HF];
    int g = blockIdx.x;
    int lo = 0, hi = N;
    while (lo < hi) { int m = (lo + hi) >> 1; if (batch[m] < g) lo = m + 1; else hi = m; }
    int s0 = lo;
    lo = s0; hi = N;
    while (lo < hi) { int m = (lo + hi) >> 1; if (batch[m] < g + 1) lo = m + 1; else hi = m; }
    int s1 = lo;
    int f = threadIdx.x;
    if (f < HF) {
        float sum = 0.f;
        for (int n = s0; n < s1; ++n) sum += xin[(size_t)n * HF + f];
        float inv = 1.0f / fmaxf((float)(s1 - s0), 1.0f);
        row[f] = sum * inv;
    }
    __syncthreads();
    if (f < HF) {
        float acc = b1[f];
        for (int k = 0; k < HF; ++k) acc = fmaf(row[k], W1[k * HF + f], acc);
        tmp1[g * HF + f] = acc;
        atomicAdd(&bnsum[f], (double)acc);
        atomicAdd(&bnsum[HF + f], (double)(acc * acc));
    }
}

__global__ __launch_bounds__(128) void
head23_kernel(const float* __restrict__ tmp1, const double* __restrict__ bnsum,
              const float* __restrict__ g1, const float* __restrict__ be1,
              const float* __restrict__ W2, const float* __restrict__ b2,
              const float* __restrict__ W3, const float* __restrict__ b3,
              float* __restrict__ out) {
    __shared__ float row[HF], row2[HF];
    int g = blockIdx.x;
    int f = threadIdx.x;
    if (f < HF) {
        double mu = bnsum[f] / (double)NGRAPHS;
        double var = bnsum[HF + f] / (double)NGRAPHS - mu * mu;
        float v = fmaxf((float)var, 0.f) + EPS;
        float a = g1[f] / sqrtf(v);
        float bb = be1[f] - (float)mu * a;
        row[f] = fmaxf(fmaf(tmp1[g * HF + f], a, bb), 0.f);
    }
    __syncthreads();
    if (f < HF) {
        float acc = b2[f];
        for (int k = 0; k < HF; ++k) acc = fmaf(row[k], W2[k * HF + f], acc);
        row2[f] = fmaxf(acc, 0.f);
    }
    __syncthreads();
    if (f < 10) {
        float acc = b3[f];
        for (int k = 0; k < HF; ++k) acc = fmaf(row2[k], W3[k * 10 + f], acc);
        out[g * 10 + f] = acc;
    }
}

// ---------------- launch ----------------

extern "C" void kernel_launch(void* const* d_in, const int* in_sizes, int n_in,
                              void* d_out, int out_size, void* d_ws, size_t ws_size,
                              hipStream_t stream) {
    (void)n_in; (void)out_size; (void)ws_size;
    const float* x     = (const float*)d_in[0];
    const int*   ei    = (const int*)d_in[1];
    const int*   batch = (const int*)d_in[2];
    const float* convW = (const float*)d_in[3];
    const float* convB = (const float*)d_in[4];
    const float* bnG   = (const float*)d_in[5];
    const float* bnB   = (const float*)d_in[6];
    const float* W1    = (const float*)d_in[7];
    const float* b1    = (const float*)d_in[8];
    const float* g1    = (const float*)d_in[9];
    const float* be1   = (const float*)d_in[10];
    const float* W2    = (const float*)d_in[11];
    const float* b2    = (const float*)d_in[12];
    const float* W3    = (const float*)d_in[13];
    const float* b3    = (const float*)d_in[14];
    float* outp = (float*)d_out;

    int N = in_sizes[0] / HF;
    int E = in_sizes[1] / 2;
    int NB = (N + 255) / 256;
    const int* src  = ei;
    const int* dstp = ei + E;

    char* ws = (char*)d_ws;
    size_t off = 0;
    auto alloc = [&](size_t bytes) -> char* {
        char* p = ws + off;
        off += (bytes + 255) & ~(size_t)255;
        return p;
    };
    __half* Hb     = (__half*)alloc((size_t)N * HF * 2);
    float* Ob      = (float*)alloc((size_t)N * HF * 4);
    int2*  csr     = (int2*)alloc((size_t)E * 8);
    int*   row_ptr = (int*)alloc((size_t)(N + 1) * 4);
    float* dinv    = (float*)alloc((size_t)N * 4);
    float* selfw   = (float*)alloc((size_t)N * 4);
    int*   bsum    = (int*)alloc((size_t)NB * 4);
    int*   boff    = (int*)alloc((size_t)NB * 4);
    float* tmp1    = (float*)alloc((size_t)NGRAPHS * HF * 4);
    char* zstart   = ws + off;
    int*    cnt    = (int*)alloc((size_t)N * 4);
    double* bns    = (double*)alloc(6 * 2 * HF * 8);   // 5 conv BN + 1 head BN
    size_t zbytes  = (size_t)((ws + off) - zstart);

    hipMemsetAsync(zstart, 0, zbytes, stream);

    count_kernel<<<1024, 256, 0, stream>>>(dstp, E, cnt);
    node_init_kernel<<<(N + 255) / 256, 256, 0, stream>>>(cnt, N, dinv, selfw);
    scan1_kernel<<<NB, 256, 0, stream>>>(cnt, N, bsum);
    scan2_kernel<<<1, 256, 0, stream>>>(bsum, NB, boff, row_ptr, N);
    scan3_kernel<<<NB, 256, 0, stream>>>(cnt, N, boff, row_ptr);
    scatter_kernel<<<1024, 256, 0, stream>>>(src, dstp, E, row_ptr, cnt, dinv, csr);

    int agg_grid = (N * CPP + 255) / 256;    // one (node, line-chunk) per thread per pass
    const float* cur = x;
    for (int i = 0; i < 6; ++i) {
        int nG = (N + 3) >> 2;
        int mm_grid = (nG * C4 + 255) / 256;
        matmul_kernel<<<mm_grid, 256, 0, stream>>>(
            cur, convW + (size_t)i * HF * HF, Hb, N,
            (i > 0) ? 1 : 0,
            (i > 0) ? bns + (size_t)(i - 1) * 2 * HF : nullptr,
            (i > 0) ? bnG + (size_t)(i - 1) * HF : nullptr,
            (i > 0) ? bnB + (size_t)(i - 1) * HF : nullptr);
        for (int pass = 0; pass < NPASS; ++pass) {
            agg_pass_kernel<<<agg_grid, 256, 0, stream>>>(
                Hb, Ob, row_ptr, csr, selfw,
                convB + (size_t)i * HF, N, pass * CPP,
                (i < 5) ? bns + (size_t)i * 2 * HF : nullptr);
        }
        cur = Ob;
    }

    pool_head1_kernel<<<NGRAPHS, 128, 0, stream>>>(Ob, batch, N, W1, b1, tmp1, bns + 5 * 2 * HF);
    head23_kernel<<<NGRAPHS, 128, 0, stream>>>(tmp1, bns + 5 * 2 * HF, g1, be1, W2, b2, W3, b3, outp);
}

// Round 11
// 750.503 us; speedup vs baseline: 2.0109x; 1.4353x over previous
//
#include <hip/hip_runtime.h>
#include <hip/hip_fp16.h>

#define HF 96
#define C4 24          // float4 chunks per f32 row
#define CH 12          // uint4 (8-half) chunks per f16 row
#define NGRAPHS 500
#define POOL_SL 8      // node slices per graph in pool kernel
#define MMROWS 64      // nodes per matmul block
#define ATP 104        // padded LDS row (halves): 208B stride -> conflict-free-ish
#define EPS 1e-5f

typedef _Float16 half8 __attribute__((ext_vector_type(8)));
typedef float f32x4 __attribute__((ext_vector_type(4)));

__device__ __forceinline__ float4 h4tof4(uint2 u) {
    __half2 a = *(__half2*)&u.x;
    __half2 b = *(__half2*)&u.y;
    float2 fa = __half22float2(a);
    float2 fb = __half22float2(b);
    return make_float4(fa.x, fa.y, fb.x, fb.y);
}

// ---------------- CSR build ----------------

__global__ void count_kernel(const int* __restrict__ dst, int E, int* __restrict__ cnt) {
    int stride = gridDim.x * blockDim.x;
    for (int i = blockIdx.x * blockDim.x + threadIdx.x; i < E; i += stride)
        atomicAdd(&cnt[dst[i]], 1);
}

__global__ void node_init_kernel(const int* __restrict__ cnt, int N,
                                 float* __restrict__ dinv, float* __restrict__ selfw) {
    int stride = gridDim.x * blockDim.x;
    for (int i = blockIdx.x * blockDim.x + threadIdx.x; i < N; i += stride) {
        float d = (float)(cnt[i] + 1);      // +1 self loop
        dinv[i] = 1.0f / sqrtf(d);
        selfw[i] = 1.0f / d;
    }
}

__global__ void scan1_kernel(const int* __restrict__ cnt, int N, int* __restrict__ bsum) {
    __shared__ int s[256];
    int t = threadIdx.x;
    int i = blockIdx.x * 256 + t;
    s[t] = (i < N) ? cnt[i] : 0;
    __syncthreads();
    for (int off = 128; off; off >>= 1) {
        if (t < off) s[t] += s[t + off];
        __syncthreads();
    }
    if (t == 0) bsum[blockIdx.x] = s[0];
}

__global__ void scan2_kernel(const int* __restrict__ bsum, int NB,
                             int* __restrict__ boff, int* __restrict__ row_ptr, int N) {
    __shared__ int s[256];
    int t = threadIdx.x;
    int v = (t < NB) ? bsum[t] : 0;
    s[t] = v;
    __syncthreads();
    for (int off = 1; off < 256; off <<= 1) {
        int u = (t >= off) ? s[t - off] : 0;
        __syncthreads();
        s[t] += u;
        __syncthreads();
    }
    if (t < NB) boff[t] = s[t] - v;
    if (t == 255) row_ptr[N] = s[255];
}

__global__ void scan3_kernel(int* __restrict__ cnt, int N, const int* __restrict__ boff,
                             int* __restrict__ row_ptr) {
    __shared__ int s[256];
    int t = threadIdx.x;
    int i = blockIdx.x * 256 + t;
    int v = (i < N) ? cnt[i] : 0;
    s[t] = v;
    __syncthreads();
    for (int off = 1; off < 256; off <<= 1) {
        int u = (t >= off) ? s[t - off] : 0;
        __syncthreads();
        s[t] += u;
        __syncthreads();
    }
    if (i < N) {
        row_ptr[i] = boff[blockIdx.x] + s[t] - v;
        cnt[i] = 0;
    }
}

__global__ void scatter_kernel(const int* __restrict__ src, const int* __restrict__ dst, int E,
                               const int* __restrict__ row_ptr, int* __restrict__ cnt,
                               const float* __restrict__ dinv,
                               int2* __restrict__ csr) {
    int stride = gridDim.x * blockDim.x;
    for (int i = blockIdx.x * blockDim.x + threadIdx.x; i < E; i += stride) {
        int d = dst[i], s = src[i];
        int p = row_ptr[d] + atomicAdd(&cnt[d], 1);
        float w = dinv[s] * dinv[d];
        csr[p] = make_int2(s, __float_as_int(w));
    }
}

// ---------------- per-layer: MFMA matmul (fused BN+ReLU of prev layer), f16 output ----------------
// block: 256 threads = 4 waves; 64 nodes x 96 features per block.
// LDS: At[64][ATP] f16 (BN+ReLU'd input), Wt[96][ATP] f16 (W transposed).
// wave w: nodes w*16..w*16+15; 6 f-tiles x 3 k-steps of mfma_f32_16x16x32_f16.

__global__ __launch_bounds__(256) void
matmul_kernel(const float* __restrict__ in, const float* __restrict__ W,
              _Float16* __restrict__ out, int N, int applyBN,
              const double* __restrict__ bnsum,
              const float* __restrict__ bnG, const float* __restrict__ bnB) {
    __shared__ _Float16 At[MMROWS][ATP];
    __shared__ _Float16 Wt[HF][ATP];
    __shared__ float sAl[HF], sBe[HF];
    int t = threadIdx.x;
    int n0 = blockIdx.x * MMROWS;
    int rows = N - n0; if (rows > MMROWS) rows = MMROWS;

    if (t < HF) {
        float a = 1.f, b = 0.f;
        if (applyBN) {
            double invN = 1.0 / (double)N;
            double mu = bnsum[t] * invN;
            double var = bnsum[HF + t] * invN - mu * mu;
            float v = fmaxf((float)var, 0.f) + EPS;
            a = bnG[t] / sqrtf(v);
            b = bnB[t] - (float)mu * a;
        }
        sAl[t] = a; sBe[t] = b;
    }
    __syncthreads();

    // stage A: 64 rows x 24 float4 = 1536 items, 6 per thread
#pragma unroll
    for (int j = 0; j < 6; ++j) {
        int gi = t + j * 256;
        int r = gi / C4, c4 = gi % C4;
        if (r < rows) {
            float4 v = ((const float4*)(in + (size_t)(n0 + r) * HF))[c4];
            int k = c4 * 4;
            if (applyBN) {
                v.x = fmaxf(fmaf(v.x, sAl[k + 0], sBe[k + 0]), 0.f);
                v.y = fmaxf(fmaf(v.y, sAl[k + 1], sBe[k + 1]), 0.f);
                v.z = fmaxf(fmaf(v.z, sAl[k + 2], sBe[k + 2]), 0.f);
                v.w = fmaxf(fmaf(v.w, sAl[k + 3], sBe[k + 3]), 0.f);
            }
            At[r][k + 0] = (_Float16)v.x; At[r][k + 1] = (_Float16)v.y;
            At[r][k + 2] = (_Float16)v.z; At[r][k + 3] = (_Float16)v.w;
        }
    }
    // stage W^T: 96 rows x 24 float4 = 2304 items, 9 per thread
#pragma unroll
    for (int j = 0; j < 9; ++j) {
        int gi = t + j * 256;
        int k = gi / C4, f4 = gi % C4;
        float4 v = ((const float4*)(W + (size_t)k * HF))[f4];
        int f = f4 * 4;
        Wt[f + 0][k] = (_Float16)v.x; Wt[f + 1][k] = (_Float16)v.y;
        Wt[f + 2][k] = (_Float16)v.z; Wt[f + 3][k] = (_Float16)v.w;
    }
    __syncthreads();

    int w = t >> 6;            // wave id 0..3
    int lane = t & 63;
    int arow = w * 16 + (lane & 15);
    int k0 = (lane >> 4) * 8;
    f32x4 acc[6];
#pragma unroll
    for (int ft = 0; ft < 6; ++ft) acc[ft] = (f32x4){0.f, 0.f, 0.f, 0.f};
#pragma unroll
    for (int ks = 0; ks < 3; ++ks) {
        half8 a = *(const half8*)&At[arow][ks * 32 + k0];
#pragma unroll
        for (int ft = 0; ft < 6; ++ft) {
            half8 b = *(const half8*)&Wt[ft * 16 + (lane & 15)][ks * 32 + k0];
            acc[ft] = __builtin_amdgcn_mfma_f32_16x16x32_f16(a, b, acc[ft], 0, 0, 0);
        }
    }
    // D: col = lane&15, row = (lane>>4)*4 + j
    int fcol = lane & 15;
#pragma unroll
    for (int ft = 0; ft < 6; ++ft) {
#pragma unroll
        for (int j = 0; j < 4; ++j) {
            int r = w * 16 + (lane >> 4) * 4 + j;
            if (r < rows)
                out[(size_t)(n0 + r) * HF + ft * 16 + fcol] = (_Float16)acc[ft][j];
        }
    }
}

// ---------------- per-layer: edge aggregation (+ BN stats), f16 gathers ----------------

__global__ __launch_bounds__(256) void
agg_kernel(const __half* __restrict__ Hb, float* __restrict__ out,
           const int* __restrict__ row_ptr, const int2* __restrict__ csr,
           const float* __restrict__ selfw, const float* __restrict__ convB,
           int N, double* __restrict__ bnsum) {
    __shared__ float sred[2 * HF];
    bool stats = (bnsum != nullptr);
    for (int i = threadIdx.x; i < 2 * HF; i += blockDim.x) sred[i] = 0.f;
    __syncthreads();
    const uint4* h4p = (const uint4*)Hb;     // row = CH uint4 chunks of 8 halfs
    int total = N * CH;
    int stride = gridDim.x * blockDim.x;
    for (int idx = blockIdx.x * blockDim.x + threadIdx.x; idx < total; idx += stride) {
        int n = idx / CH, c = idx % CH;
        const uint4* hp = h4p + c;           // lane-fixed chunk offset
        int p0 = row_ptr[n], p1 = row_ptr[n + 1];
        float sw = selfw[n];
        uint4 hraw = hp[(size_t)n * CH];
        float4 hlo = h4tof4(make_uint2(hraw.x, hraw.y));
        float4 hhi = h4tof4(make_uint2(hraw.z, hraw.w));
        float4 blo = ((const float4*)convB)[2 * c];
        float4 bhi = ((const float4*)convB)[2 * c + 1];
        float4 alo, ahi;
        alo.x = fmaf(sw, hlo.x, blo.x); alo.y = fmaf(sw, hlo.y, blo.y);
        alo.z = fmaf(sw, hlo.z, blo.z); alo.w = fmaf(sw, hlo.w, blo.w);
        ahi.x = fmaf(sw, hhi.x, bhi.x); ahi.y = fmaf(sw, hhi.y, bhi.y);
        ahi.z = fmaf(sw, hhi.z, bhi.z); ahi.w = fmaf(sw, hhi.w, bhi.w);
#define EDGE(EV, RV) { \
            float w = __int_as_float(EV.y); \
            float4 vlo = h4tof4(make_uint2(RV.x, RV.y)); \
            float4 vhi = h4tof4(make_uint2(RV.z, RV.w)); \
            alo.x = fmaf(w, vlo.x, alo.x); alo.y = fmaf(w, vlo.y, alo.y); \
            alo.z = fmaf(w, vlo.z, alo.z); alo.w = fmaf(w, vlo.w, alo.w); \
            ahi.x = fmaf(w, vhi.x, ahi.x); ahi.y = fmaf(w, vhi.y, ahi.y); \
            ahi.z = fmaf(w, vhi.z, ahi.z); ahi.w = fmaf(w, vhi.w, ahi.w); }
        int p = p0;
        for (; p + 4 <= p1; p += 4) {
            int2 e0 = csr[p], e1 = csr[p + 1], e2 = csr[p + 2], e3 = csr[p + 3];
            uint4 g0 = hp[(size_t)e0.x * CH];
            uint4 g1 = hp[(size_t)e1.x * CH];
            uint4 g2 = hp[(size_t)e2.x * CH];
            uint4 g3 = hp[(size_t)e3.x * CH];
            EDGE(e0, g0) EDGE(e1, g1) EDGE(e2, g2) EDGE(e3, g3)
        }
        for (; p < p1; ++p) {
            int2 e = csr[p];
            uint4 g = hp[(size_t)e.x * CH];
            EDGE(e, g)
        }
#undef EDGE
        ((float4*)out)[2 * idx]     = alo;
        ((float4*)out)[2 * idx + 1] = ahi;
        if (stats) {
            int f = 8 * c;
            atomicAdd(&sred[f + 0], alo.x); atomicAdd(&sred[f + 1], alo.y);
            atomicAdd(&sred[f + 2], alo.z); atomicAdd(&sred[f + 3], alo.w);
            atomicAdd(&sred[f + 4], ahi.x); atomicAdd(&sred[f + 5], ahi.y);
            atomicAdd(&sred[f + 6], ahi.z); atomicAdd(&sred[f + 7], ahi.w);
            atomicAdd(&sred[HF + f + 0], alo.x * alo.x); atomicAdd(&sred[HF + f + 1], alo.y * alo.y);
            atomicAdd(&sred[HF + f + 2], alo.z * alo.z); atomicAdd(&sred[HF + f + 3], alo.w * alo.w);
            atomicAdd(&sred[HF + f + 4], ahi.x * ahi.x); atomicAdd(&sred[HF + f + 5], ahi.y * ahi.y);
            atomicAdd(&sred[HF + f + 6], ahi.z * ahi.z); atomicAdd(&sred[HF + f + 7], ahi.w * ahi.w);
        }
    }
    if (stats) {
        __syncthreads();
        for (int i = threadIdx.x; i < 2 * HF; i += blockDim.x)
            atomicAdd(&bnsum[i], (double)sred[i]);
    }
}

// ---------------- pooling (parallel partial sums) + head ----------------

__global__ __launch_bounds__(256) void
pool_kernel(const float* __restrict__ xin, const int* __restrict__ batch, int N,
            float* __restrict__ pooled) {
    int idx = blockIdx.x * blockDim.x + threadIdx.x;
    int total = NGRAPHS * POOL_SL * C4;
    if (idx >= total) return;
    int c = idx % C4;
    int q = (idx / C4) % POOL_SL;
    int g = idx / (C4 * POOL_SL);
    int lo = 0, hi = N;
    while (lo < hi) { int m = (lo + hi) >> 1; if (batch[m] < g) lo = m + 1; else hi = m; }
    int s0 = lo;
    lo = s0; hi = N;
    while (lo < hi) { int m = (lo + hi) >> 1; if (batch[m] < g + 1) lo = m + 1; else hi = m; }
    int len = lo - s0;
    int n0 = s0 + (len * q) / POOL_SL;
    int n1 = s0 + (len * (q + 1)) / POOL_SL;
    const float4* x4 = (const float4*)xin;
    float4 acc = make_float4(0.f, 0.f, 0.f, 0.f);
    for (int n = n0; n < n1; ++n) {
        float4 v0 = x4[(size_t)n * C4 + c];
        acc.x += v0.x; acc.y += v0.y; acc.z += v0.z; acc.w += v0.w;
    }
    atomicAdd(&pooled[g * HF + 4 * c + 0], acc.x);
    atomicAdd(&pooled[g * HF + 4 * c + 1], acc.y);
    atomicAdd(&pooled[g * HF + 4 * c + 2], acc.z);
    atomicAdd(&pooled[g * HF + 4 * c + 3], acc.w);
}

__global__ __launch_bounds__(128) void
head1_kernel(const float* __restrict__ pooled, const int* __restrict__ batch, int N,
             const float* __restrict__ W1, const float* __restrict__ b1,
             float* __restrict__ tmp1, double* __restrict__ bnsum) {
    __shared__ float row[HF];
    int g = blockIdx.x;
    int lo = 0, hi = N;
    while (lo < hi) { int m = (lo + hi) >> 1; if (batch[m] < g) lo = m + 1; else hi = m; }
    int s0 = lo;
    lo = s0; hi = N;
    while (lo < hi) { int m = (lo + hi) >> 1; if (batch[m] < g + 1) lo = m + 1; else hi = m; }
    int len = lo - s0;
    float inv = 1.0f / fmaxf((float)len, 1.0f);
    int f = threadIdx.x;
    if (f < HF) row[f] = pooled[g * HF + f] * inv;
    __syncthreads();
    if (f < HF) {
        float acc = b1[f];
        for (int k = 0; k < HF; ++k) acc = fmaf(row[k], W1[k * HF + f], acc);
        tmp1[g * HF + f] = acc;
        atomicAdd(&bnsum[f], (double)acc);
        atomicAdd(&bnsum[HF + f], (double)(acc * acc));
    }
}

__global__ __launch_bounds__(128) void
head23_kernel(const float* __restrict__ tmp1, const double* __restrict__ bnsum,
              const float* __restrict__ g1, const float* __restrict__ be1,
              const float* __restrict__ W2, const float* __restrict__ b2,
              const float* __restrict__ W3, const float* __restrict__ b3,
              float* __restrict__ out) {
    __shared__ float row[HF], row2[HF];
    int g = blockIdx.x;
    int f = threadIdx.x;
    if (f < HF) {
        double mu = bnsum[f] / (double)NGRAPHS;
        double var = bnsum[HF + f] / (double)NGRAPHS - mu * mu;
        float v = fmaxf((float)var, 0.f) + EPS;
        float a = g1[f] / sqrtf(v);
        float bb = be1[f] - (float)mu * a;
        row[f] = fmaxf(fmaf(tmp1[g * HF + f], a, bb), 0.f);
    }
    __syncthreads();
    if (f < HF) {
        float acc = b2[f];
        for (int k = 0; k < HF; ++k) acc = fmaf(row[k], W2[k * HF + f], acc);
        row2[f] = fmaxf(acc, 0.f);
    }
    __syncthreads();
    if (f < 10) {
        float acc = b3[f];
        for (int k = 0; k < HF; ++k) acc = fmaf(row2[k], W3[k * 10 + f], acc);
        out[g * 10 + f] = acc;
    }
}

// ---------------- launch ----------------

extern "C" void kernel_launch(void* const* d_in, const int* in_sizes, int n_in,
                              void* d_out, int out_size, void* d_ws, size_t ws_size,
                              hipStream_t stream) {
    (void)n_in; (void)out_size; (void)ws_size;
    const float* x     = (const float*)d_in[0];
    const int*   ei    = (const int*)d_in[1];
    const int*   batch = (const int*)d_in[2];
    const float* convW = (const float*)d_in[3];
    const float* convB = (const float*)d_in[4];
    const float* bnG   = (const float*)d_in[5];
    const float* bnB   = (const float*)d_in[6];
    const float* W1    = (const float*)d_in[7];
    const float* b1    = (const float*)d_in[8];
    const float* g1    = (const float*)d_in[9];
    const float* be1   = (const float*)d_in[10];
    const float* W2    = (const float*)d_in[11];
    const float* b2    = (const float*)d_in[12];
    const float* W3    = (const float*)d_in[13];
    const float* b3    = (const float*)d_in[14];
    float* outp = (float*)d_out;

    int N = in_sizes[0] / HF;
    int E = in_sizes[1] / 2;
    int NB = (N + 255) / 256;
    const int* src  = ei;
    const int* dstp = ei + E;

    char* ws = (char*)d_ws;
    size_t off = 0;
    auto alloc = [&](size_t bytes) -> char* {
        char* p = ws + off;
        off += (bytes + 255) & ~(size_t)255;
        return p;
    };
    _Float16* Hb   = (_Float16*)alloc((size_t)N * HF * 2);
    float* Ob      = (float*)alloc((size_t)N * HF * 4);
    int2*  csr     = (int2*)alloc((size_t)E * 8);
    int*   row_ptr = (int*)alloc((size_t)(N + 1) * 4);
    float* dinv    = (float*)alloc((size_t)N * 4);
    float* selfw   = (float*)alloc((size_t)N * 4);
    int*   bsum    = (int*)alloc((size_t)NB * 4);
    int*   boff    = (int*)alloc((size_t)NB * 4);
    float* tmp1    = (float*)alloc((size_t)NGRAPHS * HF * 4);
    char* zstart   = ws + off;
    int*    cnt    = (int*)alloc((size_t)N * 4);
    double* bns    = (double*)alloc(6 * 2 * HF * 8);   // 5 conv BN + 1 head BN
    float*  pooled = (float*)alloc((size_t)NGRAPHS * HF * 4);
    size_t zbytes  = (size_t)((ws + off) - zstart);

    hipMemsetAsync(zstart, 0, zbytes, stream);

    count_kernel<<<1024, 256, 0, stream>>>(dstp, E, cnt);
    node_init_kernel<<<(N + 255) / 256, 256, 0, stream>>>(cnt, N, dinv, selfw);
    scan1_kernel<<<NB, 256, 0, stream>>>(cnt, N, bsum);
    scan2_kernel<<<1, 256, 0, stream>>>(bsum, NB, boff, row_ptr, N);
    scan3_kernel<<<NB, 256, 0, stream>>>(cnt, N, boff, row_ptr);
    scatter_kernel<<<1024, 256, 0, stream>>>(src, dstp, E, row_ptr, cnt, dinv, csr);

    int agg_grid = (N * CH + 255) / 256;     // one (node,chunk) item per thread
    int mm_grid = (N + MMROWS - 1) / MMROWS;
    const float* cur = x;
    for (int i = 0; i < 6; ++i) {
        matmul_kernel<<<mm_grid, 256, 0, stream>>>(
            cur, convW + (size_t)i * HF * HF, Hb, N,
            (i > 0) ? 1 : 0,
            (i > 0) ? bns + (size_t)(i - 1) * 2 * HF : nullptr,
            (i > 0) ? bnG + (size_t)(i - 1) * HF : nullptr,
            (i > 0) ? bnB + (size_t)(i - 1) * HF : nullptr);
        agg_kernel<<<agg_grid, 256, 0, stream>>>(
            (const __half*)Hb, Ob, row_ptr, csr, selfw,
            convB + (size_t)i * HF, N,
            (i < 5) ? bns + (size_t)i * 2 * HF : nullptr);
        cur = Ob;
    }

    int pool_grid = (NGRAPHS * POOL_SL * C4 + 255) / 256;
    pool_kernel<<<pool_grid, 256, 0, stream>>>(Ob, batch, N, pooled);
    head1_kernel<<<NGRAPHS, 128, 0, stream>>>(pooled, batch, N, W1, b1, tmp1, bns + 5 * 2 * HF);
    head23_kernel<<<NGRAPHS, 128, 0, stream>>>(tmp1, bns + 5 * 2 * HF, g1, be1, W2, b2, W3, b3, outp);
}

// Round 13
// 725.341 us; speedup vs baseline: 2.0806x; 1.0347x over previous
//
#include <hip/hip_runtime.h>
#include <hip/hip_fp16.h>

#define HF 96
#define C4 24          // float4 chunks per f32 row
#define CH 12          // uint4 (8-half) chunks per f16 row
#define NGRAPHS 500
#define MMROWS 64      // nodes per matmul block
#define ATP 104        // padded LDS row (halves)
#define PSL 20         // pool slices per graph
#define EPS 1e-5f

typedef _Float16 half8 __attribute__((ext_vector_type(8)));
typedef float f32x4 __attribute__((ext_vector_type(4)));

__device__ __forceinline__ float4 h4tof4(uint2 u) {
    __half2 a = *(__half2*)&u.x;
    __half2 b = *(__half2*)&u.y;
    float2 fa = __half22float2(a);
    float2 fb = __half22float2(b);
    return make_float4(fa.x, fa.y, fb.x, fb.y);
}
__device__ __forceinline__ uint2 f4toh4(float4 v) {
    __half2 a = __floats2half2_rn(v.x, v.y);
    __half2 b = __floats2half2_rn(v.z, v.w);
    return make_uint2(*(unsigned int*)&a, *(unsigned int*)&b);
}

// ---------------- CSR build ----------------

__global__ void count_kernel(const int* __restrict__ dst, int E, int* __restrict__ cnt) {
    int stride = gridDim.x * blockDim.x;
    for (int i = blockIdx.x * blockDim.x + threadIdx.x; i < E; i += stride)
        atomicAdd(&cnt[dst[i]], 1);
}

__global__ void scan1_kernel(const int* __restrict__ cnt, int N, int* __restrict__ bsum) {
    __shared__ int s[256];
    int t = threadIdx.x;
    int i = blockIdx.x * 256 + t;
    s[t] = (i < N) ? cnt[i] : 0;
    __syncthreads();
    for (int off = 128; off; off >>= 1) {
        if (t < off) s[t] += s[t + off];
        __syncthreads();
    }
    if (t == 0) bsum[blockIdx.x] = s[0];
}

__global__ void scan2_kernel(const int* __restrict__ bsum, int NB,
                             int* __restrict__ boff, int* __restrict__ row_ptr, int N) {
    __shared__ int s[256];
    int t = threadIdx.x;
    int v = (t < NB) ? bsum[t] : 0;
    s[t] = v;
    __syncthreads();
    for (int off = 1; off < 256; off <<= 1) {
        int u = (t >= off) ? s[t - off] : 0;
        __syncthreads();
        s[t] += u;
        __syncthreads();
    }
    if (t < NB) boff[t] = s[t] - v;
    if (t == 255) row_ptr[N] = s[255];
}

// scan3 + node_init fused
__global__ void scan3_kernel(int* __restrict__ cnt, int N, const int* __restrict__ boff,
                             int* __restrict__ row_ptr,
                             float* __restrict__ dinv, float* __restrict__ selfw) {
    __shared__ int s[256];
    int t = threadIdx.x;
    int i = blockIdx.x * 256 + t;
    int v = (i < N) ? cnt[i] : 0;
    s[t] = v;
    __syncthreads();
    for (int off = 1; off < 256; off <<= 1) {
        int u = (t >= off) ? s[t - off] : 0;
        __syncthreads();
        s[t] += u;
        __syncthreads();
    }
    if (i < N) {
        row_ptr[i] = boff[blockIdx.x] + s[t] - v;
        float d = (float)(v + 1);            // +1 self loop
        dinv[i] = 1.0f / sqrtf(d);
        selfw[i] = 1.0f / d;
        cnt[i] = 0;                          // re-zero for scatter phase
    }
}

__global__ void scatter_kernel(const int* __restrict__ src, const int* __restrict__ dst, int E,
                               const int* __restrict__ row_ptr, int* __restrict__ cnt,
                               const float* __restrict__ dinv,
                               int2* __restrict__ csr) {
    int stride = gridDim.x * blockDim.x;
    for (int i = blockIdx.x * blockDim.x + threadIdx.x; i < E; i += stride) {
        int d = dst[i], s = src[i];
        int p = row_ptr[d] + atomicAdd(&cnt[d], 1);
        float w = dinv[s] * dinv[d];
        csr[p] = make_int2(s, __float_as_int(w));
    }
}

// ---------------- per-layer: MFMA matmul (fused BN+ReLU of prev layer), f16 in/out ----------------

__global__ __launch_bounds__(256) void
matmul_kernel(const float* __restrict__ in32, const __half* __restrict__ inH,
              const float* __restrict__ W, _Float16* __restrict__ out, int N, int applyBN,
              const double* __restrict__ bnsum,
              const float* __restrict__ bnG, const float* __restrict__ bnB) {
    __shared__ _Float16 At[MMROWS][ATP];
    __shared__ _Float16 Wt[HF][ATP];
    __shared__ float sAl[HF], sBe[HF];
    int t = threadIdx.x;
    int n0 = blockIdx.x * MMROWS;
    int rows = N - n0; if (rows > MMROWS) rows = MMROWS;

    if (t < HF) {
        float a = 1.f, b = 0.f;
        if (applyBN) {
            double invN = 1.0 / (double)N;
            double mu = bnsum[t] * invN;
            double var = bnsum[HF + t] * invN - mu * mu;
            float v = fmaxf((float)var, 0.f) + EPS;
            a = bnG[t] / sqrtf(v);
            b = bnB[t] - (float)mu * a;
        }
        sAl[t] = a; sBe[t] = b;
    }
    __syncthreads();

    if (inH) {
        // stage A from f16: 64 rows x 12 uint4 = 768 items, 3 per thread
#pragma unroll
        for (int j = 0; j < 3; ++j) {
            int gi = t + j * 256;
            int r = gi / CH, ch = gi % CH;
            if (r < rows) {
                uint4 u = ((const uint4*)(inH + (size_t)(n0 + r) * HF))[ch];
                float4 lo = h4tof4(make_uint2(u.x, u.y));
                float4 hi = h4tof4(make_uint2(u.z, u.w));
                int k = ch * 8;
                if (applyBN) {
                    lo.x = fmaxf(fmaf(lo.x, sAl[k + 0], sBe[k + 0]), 0.f);
                    lo.y = fmaxf(fmaf(lo.y, sAl[k + 1], sBe[k + 1]), 0.f);
                    lo.z = fmaxf(fmaf(lo.z, sAl[k + 2], sBe[k + 2]), 0.f);
                    lo.w = fmaxf(fmaf(lo.w, sAl[k + 3], sBe[k + 3]), 0.f);
                    hi.x = fmaxf(fmaf(hi.x, sAl[k + 4], sBe[k + 4]), 0.f);
                    hi.y = fmaxf(fmaf(hi.y, sAl[k + 5], sBe[k + 5]), 0.f);
                    hi.z = fmaxf(fmaf(hi.z, sAl[k + 6], sBe[k + 6]), 0.f);
                    hi.w = fmaxf(fmaf(hi.w, sAl[k + 7], sBe[k + 7]), 0.f);
                }
                half8 hv;
                hv[0] = (_Float16)lo.x; hv[1] = (_Float16)lo.y;
                hv[2] = (_Float16)lo.z; hv[3] = (_Float16)lo.w;
                hv[4] = (_Float16)hi.x; hv[5] = (_Float16)hi.y;
                hv[6] = (_Float16)hi.z; hv[7] = (_Float16)hi.w;
                *(half8*)&At[r][k] = hv;
            }
        }
    } else {
        // stage A from f32 (layer 0, no BN): 64 rows x 24 float4, 6 per thread
#pragma unroll
        for (int j = 0; j < 6; ++j) {
            int gi = t + j * 256;
            int r = gi / C4, c4 = gi % C4;
            if (r < rows) {
                float4 v = ((const float4*)(in32 + (size_t)(n0 + r) * HF))[c4];
                int k = c4 * 4;
                At[r][k + 0] = (_Float16)v.x; At[r][k + 1] = (_Float16)v.y;
                At[r][k + 2] = (_Float16)v.z; At[r][k + 3] = (_Float16)v.w;
            }
        }
    }
    // stage W^T: 96 rows x 24 float4 = 2304 items, 9 per thread
#pragma unroll
    for (int j = 0; j < 9; ++j) {
        int gi = t + j * 256;
        int k = gi / C4, f4 = gi % C4;
        float4 v = ((const float4*)(W + (size_t)k * HF))[f4];
        int f = f4 * 4;
        Wt[f + 0][k] = (_Float16)v.x; Wt[f + 1][k] = (_Float16)v.y;
        Wt[f + 2][k] = (_Float16)v.z; Wt[f + 3][k] = (_Float16)v.w;
    }
    __syncthreads();

    int w = t >> 6;            // wave id 0..3
    int lane = t & 63;
    int arow = w * 16 + (lane & 15);
    int k0 = (lane >> 4) * 8;
    f32x4 acc[6];
#pragma unroll
    for (int ft = 0; ft < 6; ++ft) acc[ft] = (f32x4){0.f, 0.f, 0.f, 0.f};
#pragma unroll
    for (int ks = 0; ks < 3; ++ks) {
        half8 a = *(const half8*)&At[arow][ks * 32 + k0];
#pragma unroll
        for (int ft = 0; ft < 6; ++ft) {
            half8 b = *(const half8*)&Wt[ft * 16 + (lane & 15)][ks * 32 + k0];
            acc[ft] = __builtin_amdgcn_mfma_f32_16x16x32_f16(a, b, acc[ft], 0, 0, 0);
        }
    }
    // D: col = lane&15, row = (lane>>4)*4 + j
    int fcol = lane & 15;
#pragma unroll
    for (int ft = 0; ft < 6; ++ft) {
#pragma unroll
        for (int j = 0; j < 4; ++j) {
            int r = w * 16 + (lane >> 4) * 4 + j;
            if (r < rows)
                out[(size_t)(n0 + r) * HF + ft * 16 + fcol] = (_Float16)acc[ft][j];
        }
    }
}

// ---------------- per-layer: edge aggregation (+ BN stats), f16 gathers, f16 output ----------------

__global__ __launch_bounds__(256) void
agg_kernel(const __half* __restrict__ Hb, __half* __restrict__ out,
           const int* __restrict__ row_ptr, const int2* __restrict__ csr,
           const float* __restrict__ selfw, const float* __restrict__ convB,
           int N, double* __restrict__ bnsum) {
    __shared__ float sred[2 * HF];
    bool stats = (bnsum != nullptr);
    for (int i = threadIdx.x; i < 2 * HF; i += blockDim.x) sred[i] = 0.f;
    __syncthreads();
    const uint4* h4p = (const uint4*)Hb;     // row = CH uint4 chunks of 8 halfs
    int total = N * CH;
    int stride = gridDim.x * blockDim.x;
    for (int idx = blockIdx.x * blockDim.x + threadIdx.x; idx < total; idx += stride) {
        int n = idx / CH, c = idx % CH;
        const uint4* hp = h4p + c;           // lane-fixed chunk offset
        int p0 = row_ptr[n], p1 = row_ptr[n + 1];
        float sw = selfw[n];
        uint4 hraw = hp[(size_t)n * CH];
        float4 hlo = h4tof4(make_uint2(hraw.x, hraw.y));
        float4 hhi = h4tof4(make_uint2(hraw.z, hraw.w));
        float4 blo = ((const float4*)convB)[2 * c];
        float4 bhi = ((const float4*)convB)[2 * c + 1];
        float4 alo, ahi;
        alo.x = fmaf(sw, hlo.x, blo.x); alo.y = fmaf(sw, hlo.y, blo.y);
        alo.z = fmaf(sw, hlo.z, blo.z); alo.w = fmaf(sw, hlo.w, blo.w);
        ahi.x = fmaf(sw, hhi.x, bhi.x); ahi.y = fmaf(sw, hhi.y, bhi.y);
        ahi.z = fmaf(sw, hhi.z, bhi.z); ahi.w = fmaf(sw, hhi.w, bhi.w);
#define EDGE(EV, RV) { \
            float w = __int_as_float(EV.y); \
            float4 vlo = h4tof4(make_uint2(RV.x, RV.y)); \
            float4 vhi = h4tof4(make_uint2(RV.z, RV.w)); \
            alo.x = fmaf(w, vlo.x, alo.x); alo.y = fmaf(w, vlo.y, alo.y); \
            alo.z = fmaf(w, vlo.z, alo.z); alo.w = fmaf(w, vlo.w, alo.w); \
            ahi.x = fmaf(w, vhi.x, ahi.x); ahi.y = fmaf(w, vhi.y, ahi.y); \
            ahi.z = fmaf(w, vhi.z, ahi.z); ahi.w = fmaf(w, vhi.w, ahi.w); }
        int p = p0;
        for (; p + 4 <= p1; p += 4) {
            int2 e0 = csr[p], e1 = csr[p + 1], e2 = csr[p + 2], e3 = csr[p + 3];
            uint4 g0 = hp[(size_t)e0.x * CH];
            uint4 g1 = hp[(size_t)e1.x * CH];
            uint4 g2 = hp[(size_t)e2.x * CH];
            uint4 g3 = hp[(size_t)e3.x * CH];
            EDGE(e0, g0) EDGE(e1, g1) EDGE(e2, g2) EDGE(e3, g3)
        }
        for (; p < p1; ++p) {
            int2 e = csr[p];
            uint4 g = hp[(size_t)e.x * CH];
            EDGE(e, g)
        }
#undef EDGE
        uint2 olo = f4toh4(alo), ohi = f4toh4(ahi);
        ((uint4*)out)[idx] = make_uint4(olo.x, olo.y, ohi.x, ohi.y);
        if (stats) {
            int f = 8 * c;
            atomicAdd(&sred[f + 0], alo.x); atomicAdd(&sred[f + 1], alo.y);
            atomicAdd(&sred[f + 2], alo.z); atomicAdd(&sred[f + 3], alo.w);
            atomicAdd(&sred[f + 4], ahi.x); atomicAdd(&sred[f + 5], ahi.y);
            atomicAdd(&sred[f + 6], ahi.z); atomicAdd(&sred[f + 7], ahi.w);
            atomicAdd(&sred[HF + f + 0], alo.x * alo.x); atomicAdd(&sred[HF + f + 1], alo.y * alo.y);
            atomicAdd(&sred[HF + f + 2], alo.z * alo.z); atomicAdd(&sred[HF + f + 3], alo.w * alo.w);
            atomicAdd(&sred[HF + f + 4], ahi.x * ahi.x); atomicAdd(&sred[HF + f + 5], ahi.y * ahi.y);
            atomicAdd(&sred[HF + f + 6], ahi.z * ahi.z); atomicAdd(&sred[HF + f + 7], ahi.w * ahi.w);
        }
    }
    if (stats) {
        __syncthreads();
        for (int i = threadIdx.x; i < 2 * HF; i += blockDim.x)
            atomicAdd(&bnsum[i], (double)sred[i]);
    }
}

// ---------------- pooling + head1 (fused, block per graph) ----------------

__global__ __launch_bounds__(256) void
pool_head1_kernel(const __half* __restrict__ xin, const int* __restrict__ batch, int N,
                  const float* __restrict__ W1, const float* __restrict__ b1,
                  float* __restrict__ tmp1, double* __restrict__ bnsum) {
    __shared__ float sp[PSL][HF];
    __shared__ float row[HF];
    int g = blockIdx.x, t = threadIdx.x;
    int lo = 0, hi = N;
    while (lo < hi) { int m = (lo + hi) >> 1; if (batch[m] < g) lo = m + 1; else hi = m; }
    int s0 = lo;
    lo = s0; hi = N;
    while (lo < hi) { int m = (lo + hi) >> 1; if (batch[m] < g + 1) lo = m + 1; else hi = m; }
    int s1 = lo, len = s1 - s0;
    int c = t % CH, q = t / CH;          // q < PSL for t < 240
    if (q < PSL) {
        float4 aL = make_float4(0.f, 0.f, 0.f, 0.f), aH = aL;
        for (int n = s0 + q; n < s1; n += PSL) {
            uint4 u = ((const uint4*)(xin + (size_t)n * HF))[c];
            float4 lo4 = h4tof4(make_uint2(u.x, u.y));
            float4 hi4 = h4tof4(make_uint2(u.z, u.w));
            aL.x += lo4.x; aL.y += lo4.y; aL.z += lo4.z; aL.w += lo4.w;
            aH.x += hi4.x; aH.y += hi4.y; aH.z += hi4.z; aH.w += hi4.w;
        }
        int f = c * 8;
        sp[q][f + 0] = aL.x; sp[q][f + 1] = aL.y; sp[q][f + 2] = aL.z; sp[q][f + 3] = aL.w;
        sp[q][f + 4] = aH.x; sp[q][f + 5] = aH.y; sp[q][f + 6] = aH.z; sp[q][f + 7] = aH.w;
    }
    __syncthreads();
    float inv = 1.0f / fmaxf((float)len, 1.0f);
    if (t < HF) {
        float s = 0.f;
#pragma unroll
        for (int q2 = 0; q2 < PSL; ++q2) s += sp[q2][t];
        row[t] = s * inv;
    }
    __syncthreads();
    if (t < HF) {
        float acc = b1[t];
        for (int k = 0; k < HF; ++k) acc = fmaf(row[k], W1[k * HF + t], acc);
        tmp1[g * HF + t] = acc;
        atomicAdd(&bnsum[t], (double)acc);
        atomicAdd(&bnsum[HF + t], (double)(acc * acc));
    }
}

__global__ __launch_bounds__(128) void
head23_kernel(const float* __restrict__ tmp1, const double* __restrict__ bnsum,
              const float* __restrict__ g1, const float* __restrict__ be1,
              const float* __restrict__ W2, const float* __restrict__ b2,
              const float* __restrict__ W3, const float* __restrict__ b3,
              float* __restrict__ out) {
    __shared__ float row[HF], row2[HF];
    int g = blockIdx.x;
    int f = threadIdx.x;
    if (f < HF) {
        double mu = bnsum[f] / (double)NGRAPHS;
        double var = bnsum[HF + f] / (double)NGRAPHS - mu * mu;
        float v = fmaxf((float)var, 0.f) + EPS;
        float a = g1[f] / sqrtf(v);
        float bb = be1[f] - (float)mu * a;
        row[f] = fmaxf(fmaf(tmp1[g * HF + f], a, bb), 0.f);
    }
    __syncthreads();
    if (f < HF) {
        float acc = b2[f];
        for (int k = 0; k < HF; ++k) acc = fmaf(row[k], W2[k * HF + f], acc);
        row2[f] = fmaxf(acc, 0.f);
    }
    __syncthreads();
    if (f < 10) {
        float acc = b3[f];
        for (int k = 0; k < HF; ++k) acc = fmaf(row2[k], W3[k * 10 + f], acc);
        out[g * 10 + f] = acc;
    }
}

// ---------------- launch ----------------

extern "C" void kernel_launch(void* const* d_in, const int* in_sizes, int n_in,
                              void* d_out, int out_size, void* d_ws, size_t ws_size,
                              hipStream_t stream) {
    (void)n_in; (void)out_size; (void)ws_size;
    const float* x     = (const float*)d_in[0];
    const int*   ei    = (const int*)d_in[1];
    const int*   batch = (const int*)d_in[2];
    const float* convW = (const float*)d_in[3];
    const float* convB = (const float*)d_in[4];
    const float* bnG   = (const float*)d_in[5];
    const float* bnB   = (const float*)d_in[6];
    const float* W1    = (const float*)d_in[7];
    const float* b1    = (const float*)d_in[8];
    const float* g1    = (const float*)d_in[9];
    const float* be1   = (const float*)d_in[10];
    const float* W2    = (const float*)d_in[11];
    const float* b2    = (const float*)d_in[12];
    const float* W3    = (const float*)d_in[13];
    const float* b3    = (const float*)d_in[14];
    float* outp = (float*)d_out;

    int N = in_sizes[0] / HF;
    int E = in_sizes[1] / 2;
    int NB = (N + 255) / 256;
    const int* src  = ei;
    const int* dstp = ei + E;

    char* ws = (char*)d_ws;
    size_t off = 0;
    auto alloc = [&](size_t bytes) -> char* {
        char* p = ws + off;
        off += (bytes + 255) & ~(size_t)255;
        return p;
    };
    _Float16* Hb   = (_Float16*)alloc((size_t)N * HF * 2);
    _Float16* Ob   = (_Float16*)alloc((size_t)N * HF * 2);
    int2*  csr     = (int2*)alloc((size_t)E * 8);
    int*   row_ptr = (int*)alloc((size_t)(N + 1) * 4);
    float* dinv    = (float*)alloc((size_t)N * 4);
    float* selfw   = (float*)alloc((size_t)N * 4);
    int*   bsum    = (int*)alloc((size_t)NB * 4);
    int*   boff    = (int*)alloc((size_t)NB * 4);
    float* tmp1    = (float*)alloc((size_t)NGRAPHS * HF * 4);
    char* zstart   = ws + off;
    int*    cnt    = (int*)alloc((size_t)N * 4);
    double* bns    = (double*)alloc(6 * 2 * HF * 8);   // 5 conv BN + 1 head BN
    size_t zbytes  = (size_t)((ws + off) - zstart);

    hipMemsetAsync(zstart, 0, zbytes, stream);

    count_kernel<<<1024, 256, 0, stream>>>(dstp, E, cnt);
    scan1_kernel<<<NB, 256, 0, stream>>>(cnt, N, bsum);
    scan2_kernel<<<1, 256, 0, stream>>>(bsum, NB, boff, row_ptr, N);
    scan3_kernel<<<NB, 256, 0, stream>>>(cnt, N, boff, row_ptr, dinv, selfw);
    scatter_kernel<<<1024, 256, 0, stream>>>(src, dstp, E, row_ptr, cnt, dinv, csr);

    int agg_grid = (N * CH + 255) / 256;     // one (node,chunk) item per thread
    int mm_grid = (N + MMROWS - 1) / MMROWS;
    for (int i = 0; i < 6; ++i) {
        matmul_kernel<<<mm_grid, 256, 0, stream>>>(
            (i == 0) ? x : nullptr,
            (i == 0) ? nullptr : (const __half*)Ob,
            convW + (size_t)i * HF * HF, Hb, N,
            (i > 0) ? 1 : 0,
            (i > 0) ? bns + (size_t)(i - 1) * 2 * HF : nullptr,
            (i > 0) ? bnG + (size_t)(i - 1) * HF : nullptr,
            (i > 0) ? bnB + (size_t)(i - 1) * HF : nullptr);
        agg_kernel<<<agg_grid, 256, 0, stream>>>(
            (const __half*)Hb, (__half*)Ob, row_ptr, csr, selfw,
            convB + (size_t)i * HF, N,
            (i < 5) ? bns + (size_t)i * 2 * HF : nullptr);
    }

    pool_head1_kernel<<<NGRAPHS, 256, 0, stream>>>((const __half*)Ob, batch, N,
                                                   W1, b1, tmp1, bns + 5 * 2 * HF);
    head23_kernel<<<NGRAPHS, 128, 0, stream>>>(tmp1, bns + 5 * 2 * HF, g1, be1, W2, b2, W3, b3, outp);
}

// Round 14
// 701.489 us; speedup vs baseline: 2.1514x; 1.0340x over previous
//
#include <hip/hip_runtime.h>
#include <hip/hip_fp16.h>

#define HF 96
#define C4 24          // float4 chunks per f32 row
#define CH 12          // uint4 (8-half) chunks per f16 row
#define NGRAPHS 500
#define MMROWS 128     // nodes per matmul block
#define ATP 104        // padded LDS row (halves)
#define PSL 20         // pool slices per graph
#define EPS 1e-5f

typedef _Float16 half8 __attribute__((ext_vector_type(8)));
typedef float f32x4 __attribute__((ext_vector_type(4)));

__device__ __forceinline__ float4 h4tof4(uint2 u) {
    __half2 a = *(__half2*)&u.x;
    __half2 b = *(__half2*)&u.y;
    float2 fa = __half22float2(a);
    float2 fb = __half22float2(b);
    return make_float4(fa.x, fa.y, fb.x, fb.y);
}
__device__ __forceinline__ uint2 f4toh4(float4 v) {
    __half2 a = __floats2half2_rn(v.x, v.y);
    __half2 b = __floats2half2_rn(v.z, v.w);
    return make_uint2(*(unsigned int*)&a, *(unsigned int*)&b);
}

// ---------------- weight prep: W[6][k][f] f32 -> Wt6[6][f][k] f16 ----------------

__global__ void wprep_kernel(const float* __restrict__ W, _Float16* __restrict__ Wt6) {
    int i = blockIdx.x * blockDim.x + threadIdx.x;
    if (i >= 6 * HF * HF) return;
    int k = i % HF;
    int f = (i / HF) % HF;
    int l = i / (HF * HF);
    Wt6[i] = (_Float16)W[(size_t)l * HF * HF + (size_t)k * HF + f];
}

// ---------------- CSR build ----------------

__global__ void count_kernel(const int* __restrict__ dst, int E, int* __restrict__ cnt) {
    int stride = gridDim.x * blockDim.x;
    for (int i = blockIdx.x * blockDim.x + threadIdx.x; i < E; i += stride)
        atomicAdd(&cnt[dst[i]], 1);
}

__global__ void scan1_kernel(const int* __restrict__ cnt, int N, int* __restrict__ bsum) {
    __shared__ int s[256];
    int t = threadIdx.x;
    int i = blockIdx.x * 256 + t;
    s[t] = (i < N) ? cnt[i] : 0;
    __syncthreads();
    for (int off = 128; off; off >>= 1) {
        if (t < off) s[t] += s[t + off];
        __syncthreads();
    }
    if (t == 0) bsum[blockIdx.x] = s[0];
}

__global__ void scan2_kernel(const int* __restrict__ bsum, int NB,
                             int* __restrict__ boff, int* __restrict__ row_ptr, int N) {
    __shared__ int s[256];
    int t = threadIdx.x;
    int v = (t < NB) ? bsum[t] : 0;
    s[t] = v;
    __syncthreads();
    for (int off = 1; off < 256; off <<= 1) {
        int u = (t >= off) ? s[t - off] : 0;
        __syncthreads();
        s[t] += u;
        __syncthreads();
    }
    if (t < NB) boff[t] = s[t] - v;
    if (t == 255) row_ptr[N] = s[255];
}

// scan3 + node_init fused
__global__ void scan3_kernel(int* __restrict__ cnt, int N, const int* __restrict__ boff,
                             int* __restrict__ row_ptr,
                             float* __restrict__ dinv, float* __restrict__ selfw) {
    __shared__ int s[256];
    int t = threadIdx.x;
    int i = blockIdx.x * 256 + t;
    int v = (i < N) ? cnt[i] : 0;
    s[t] = v;
    __syncthreads();
    for (int off = 1; off < 256; off <<= 1) {
        int u = (t >= off) ? s[t - off] : 0;
        __syncthreads();
        s[t] += u;
        __syncthreads();
    }
    if (i < N) {
        row_ptr[i] = boff[blockIdx.x] + s[t] - v;
        float d = (float)(v + 1);            // +1 self loop
        dinv[i] = 1.0f / sqrtf(d);
        selfw[i] = 1.0f / d;
        cnt[i] = 0;                          // re-zero for scatter phase
    }
}

__global__ void scatter_kernel(const int* __restrict__ src, const int* __restrict__ dst, int E,
                               const int* __restrict__ row_ptr, int* __restrict__ cnt,
                               const float* __restrict__ dinv,
                               int2* __restrict__ csr) {
    int stride = gridDim.x * blockDim.x;
    for (int i = blockIdx.x * blockDim.x + threadIdx.x; i < E; i += stride) {
        int d = dst[i], s = src[i];
        int p = row_ptr[d] + atomicAdd(&cnt[d], 1);
        float w = dinv[s] * dinv[d];
        csr[p] = make_int2(s, __float_as_int(w));
    }
}

// ---------------- per-layer: MFMA matmul (fused BN+ReLU of prev layer), f16 in/out ----------------
// 512 threads = 8 waves; 128 nodes x 96 features per block. Wg = pre-transposed f16 W^T[f][k].

__global__ __launch_bounds__(512) void
matmul_kernel(const float* __restrict__ in32, const __half* __restrict__ inH,
              const _Float16* __restrict__ Wg, _Float16* __restrict__ out, int N, int applyBN,
              const double* __restrict__ bnsum,
              const float* __restrict__ bnG, const float* __restrict__ bnB) {
    __shared__ _Float16 At[MMROWS][ATP];
    __shared__ _Float16 Wt[HF][ATP];
    __shared__ float sAl[HF], sBe[HF];
    int t = threadIdx.x;
    int n0 = blockIdx.x * MMROWS;
    int rows = N - n0; if (rows > MMROWS) rows = MMROWS;

    if (t < HF) {
        float a = 1.f, b = 0.f;
        if (applyBN) {
            double invN = 1.0 / (double)N;
            double mu = bnsum[t] * invN;
            double var = bnsum[HF + t] * invN - mu * mu;
            float v = fmaxf((float)var, 0.f) + EPS;
            a = bnG[t] / sqrtf(v);
            b = bnB[t] - (float)mu * a;
        }
        sAl[t] = a; sBe[t] = b;
    }
    __syncthreads();

    if (inH) {
        // stage A from f16: 128 rows x 12 uint4 = 1536 items, 3 per thread
#pragma unroll
        for (int j = 0; j < 3; ++j) {
            int gi = t + j * 512;
            int r = gi / CH, ch = gi % CH;
            if (r < rows) {
                uint4 u = ((const uint4*)(inH + (size_t)(n0 + r) * HF))[ch];
                float4 lo = h4tof4(make_uint2(u.x, u.y));
                float4 hi = h4tof4(make_uint2(u.z, u.w));
                int k = ch * 8;
                if (applyBN) {
                    lo.x = fmaxf(fmaf(lo.x, sAl[k + 0], sBe[k + 0]), 0.f);
                    lo.y = fmaxf(fmaf(lo.y, sAl[k + 1], sBe[k + 1]), 0.f);
                    lo.z = fmaxf(fmaf(lo.z, sAl[k + 2], sBe[k + 2]), 0.f);
                    lo.w = fmaxf(fmaf(lo.w, sAl[k + 3], sBe[k + 3]), 0.f);
                    hi.x = fmaxf(fmaf(hi.x, sAl[k + 4], sBe[k + 4]), 0.f);
                    hi.y = fmaxf(fmaf(hi.y, sAl[k + 5], sBe[k + 5]), 0.f);
                    hi.z = fmaxf(fmaf(hi.z, sAl[k + 6], sBe[k + 6]), 0.f);
                    hi.w = fmaxf(fmaf(hi.w, sAl[k + 7], sBe[k + 7]), 0.f);
                }
                half8 hv;
                hv[0] = (_Float16)lo.x; hv[1] = (_Float16)lo.y;
                hv[2] = (_Float16)lo.z; hv[3] = (_Float16)lo.w;
                hv[4] = (_Float16)hi.x; hv[5] = (_Float16)hi.y;
                hv[6] = (_Float16)hi.z; hv[7] = (_Float16)hi.w;
                *(half8*)&At[r][k] = hv;
            }
        }
    } else {
        // stage A from f32 (layer 0, no BN): 128 rows x 24 float4 = 3072, 6 per thread
#pragma unroll
        for (int j = 0; j < 6; ++j) {
            int gi = t + j * 512;
            int r = gi / C4, c4 = gi % C4;
            if (r < rows) {
                float4 v = ((const float4*)(in32 + (size_t)(n0 + r) * HF))[c4];
                int k = c4 * 4;
                At[r][k + 0] = (_Float16)v.x; At[r][k + 1] = (_Float16)v.y;
                At[r][k + 2] = (_Float16)v.z; At[r][k + 3] = (_Float16)v.w;
            }
        }
    }
    // stage W^T (pre-transposed f16): 96 rows x 12 uint4 = 1152 items
#pragma unroll
    for (int j = 0; j < 3; ++j) {
        int gi = t + j * 512;
        if (gi < HF * CH) {
            int f = gi / CH, u = gi % CH;
            uint4 g = ((const uint4*)Wg)[gi];
            *(uint4*)&Wt[f][u * 8] = g;
        }
    }
    __syncthreads();

    int w = t >> 6;            // wave id 0..7
    int lane = t & 63;
    int arow = w * 16 + (lane & 15);
    int k0 = (lane >> 4) * 8;
    f32x4 acc[6];
#pragma unroll
    for (int ft = 0; ft < 6; ++ft) acc[ft] = (f32x4){0.f, 0.f, 0.f, 0.f};
#pragma unroll
    for (int ks = 0; ks < 3; ++ks) {
        half8 a = *(const half8*)&At[arow][ks * 32 + k0];
#pragma unroll
        for (int ft = 0; ft < 6; ++ft) {
            half8 b = *(const half8*)&Wt[ft * 16 + (lane & 15)][ks * 32 + k0];
            acc[ft] = __builtin_amdgcn_mfma_f32_16x16x32_f16(a, b, acc[ft], 0, 0, 0);
        }
    }
    // D: col = lane&15, row = (lane>>4)*4 + j
    int fcol = lane & 15;
#pragma unroll
    for (int ft = 0; ft < 6; ++ft) {
#pragma unroll
        for (int j = 0; j < 4; ++j) {
            int r = w * 16 + (lane >> 4) * 4 + j;
            if (r < rows)
                out[(size_t)(n0 + r) * HF + ft * 16 + fcol] = (_Float16)acc[ft][j];
        }
    }
}

// ---------------- per-layer: edge aggregation (+ BN stats), f16 gathers, f16 output ----------------

__global__ __launch_bounds__(256) void
agg_kernel(const __half* __restrict__ Hb, __half* __restrict__ out,
           const int* __restrict__ row_ptr, const int2* __restrict__ csr,
           const float* __restrict__ selfw, const float* __restrict__ convB,
           int N, double* __restrict__ bnsum) {
    __shared__ float sred[2 * HF];
    bool stats = (bnsum != nullptr);
    for (int i = threadIdx.x; i < 2 * HF; i += blockDim.x) sred[i] = 0.f;
    __syncthreads();
    const uint4* h4p = (const uint4*)Hb;     // row = CH uint4 chunks of 8 halfs
    int total = N * CH;
    int stride = gridDim.x * blockDim.x;
    for (int idx = blockIdx.x * blockDim.x + threadIdx.x; idx < total; idx += stride) {
        int n = idx / CH, c = idx % CH;
        const uint4* hp = h4p + c;           // lane-fixed chunk offset
        int p0 = row_ptr[n], p1 = row_ptr[n + 1];
        float sw = selfw[n];
        uint4 hraw = hp[(size_t)n * CH];
        float4 hlo = h4tof4(make_uint2(hraw.x, hraw.y));
        float4 hhi = h4tof4(make_uint2(hraw.z, hraw.w));
        float4 blo = ((const float4*)convB)[2 * c];
        float4 bhi = ((const float4*)convB)[2 * c + 1];
        float4 alo, ahi;
        alo.x = fmaf(sw, hlo.x, blo.x); alo.y = fmaf(sw, hlo.y, blo.y);
        alo.z = fmaf(sw, hlo.z, blo.z); alo.w = fmaf(sw, hlo.w, blo.w);
        ahi.x = fmaf(sw, hhi.x, bhi.x); ahi.y = fmaf(sw, hhi.y, bhi.y);
        ahi.z = fmaf(sw, hhi.z, bhi.z); ahi.w = fmaf(sw, hhi.w, bhi.w);
#define EDGE(EV, RV) { \
            float w = __int_as_float(EV.y); \
            float4 vlo = h4tof4(make_uint2(RV.x, RV.y)); \
            float4 vhi = h4tof4(make_uint2(RV.z, RV.w)); \
            alo.x = fmaf(w, vlo.x, alo.x); alo.y = fmaf(w, vlo.y, alo.y); \
            alo.z = fmaf(w, vlo.z, alo.z); alo.w = fmaf(w, vlo.w, alo.w); \
            ahi.x = fmaf(w, vhi.x, ahi.x); ahi.y = fmaf(w, vhi.y, ahi.y); \
            ahi.z = fmaf(w, vhi.z, ahi.z); ahi.w = fmaf(w, vhi.w, ahi.w); }
        int p = p0;
        for (; p + 4 <= p1; p += 4) {
            int2 e0 = csr[p], e1 = csr[p + 1], e2 = csr[p + 2], e3 = csr[p + 3];
            uint4 g0 = hp[(size_t)e0.x * CH];
            uint4 g1 = hp[(size_t)e1.x * CH];
            uint4 g2 = hp[(size_t)e2.x * CH];
            uint4 g3 = hp[(size_t)e3.x * CH];
            EDGE(e0, g0) EDGE(e1, g1) EDGE(e2, g2) EDGE(e3, g3)
        }
        for (; p < p1; ++p) {
            int2 e = csr[p];
            uint4 g = hp[(size_t)e.x * CH];
            EDGE(e, g)
        }
#undef EDGE
        uint2 olo = f4toh4(alo), ohi = f4toh4(ahi);
        ((uint4*)out)[idx] = make_uint4(olo.x, olo.y, ohi.x, ohi.y);
        if (stats) {
            int f = 8 * c;
            atomicAdd(&sred[f + 0], alo.x); atomicAdd(&sred[f + 1], alo.y);
            atomicAdd(&sred[f + 2], alo.z); atomicAdd(&sred[f + 3], alo.w);
            atomicAdd(&sred[f + 4], ahi.x); atomicAdd(&sred[f + 5], ahi.y);
            atomicAdd(&sred[f + 6], ahi.z); atomicAdd(&sred[f + 7], ahi.w);
            atomicAdd(&sred[HF + f + 0], alo.x * alo.x); atomicAdd(&sred[HF + f + 1], alo.y * alo.y);
            atomicAdd(&sred[HF + f + 2], alo.z * alo.z); atomicAdd(&sred[HF + f + 3], alo.w * alo.w);
            atomicAdd(&sred[HF + f + 4], ahi.x * ahi.x); atomicAdd(&sred[HF + f + 5], ahi.y * ahi.y);
            atomicAdd(&sred[HF + f + 6], ahi.z * ahi.z); atomicAdd(&sred[HF + f + 7], ahi.w * ahi.w);
        }
    }
    if (stats) {
        __syncthreads();
        for (int i = threadIdx.x; i < 2 * HF; i += blockDim.x)
            atomicAdd(&bnsum[i], (double)sred[i]);
    }
}

// ---------------- pooling + head1 (fused, block per graph) ----------------

__global__ __launch_bounds__(256) void
pool_head1_kernel(const __half* __restrict__ xin, const int* __restrict__ batch, int N,
                  const float* __restrict__ W1, const float* __restrict__ b1,
                  float* __restrict__ tmp1, double* __restrict__ bnsum) {
    __shared__ float sp[PSL][HF];
    __shared__ float row[HF];
    int g = blockIdx.x, t = threadIdx.x;
    int lo = 0, hi = N;
    while (lo < hi) { int m = (lo + hi) >> 1; if (batch[m] < g) lo = m + 1; else hi = m; }
    int s0 = lo;
    lo = s0; hi = N;
    while (lo < hi) { int m = (lo + hi) >> 1; if (batch[m] < g + 1) lo = m + 1; else hi = m; }
    int s1 = lo, len = s1 - s0;
    int c = t % CH, q = t / CH;          // q < PSL for t < 240
    if (q < PSL) {
        float4 aL = make_float4(0.f, 0.f, 0.f, 0.f), aH = aL;
        for (int n = s0 + q; n < s1; n += PSL) {
            uint4 u = ((const uint4*)(xin + (size_t)n * HF))[c];
            float4 lo4 = h4tof4(make_uint2(u.x, u.y));
            float4 hi4 = h4tof4(make_uint2(u.z, u.w));
            aL.x += lo4.x; aL.y += lo4.y; aL.z += lo4.z; aL.w += lo4.w;
            aH.x += hi4.x; aH.y += hi4.y; aH.z += hi4.z; aH.w += hi4.w;
        }
        int f = c * 8;
        sp[q][f + 0] = aL.x; sp[q][f + 1] = aL.y; sp[q][f + 2] = aL.z; sp[q][f + 3] = aL.w;
        sp[q][f + 4] = aH.x; sp[q][f + 5] = aH.y; sp[q][f + 6] = aH.z; sp[q][f + 7] = aH.w;
    }
    __syncthreads();
    float inv = 1.0f / fmaxf((float)len, 1.0f);
    if (t < HF) {
        float s = 0.f;
#pragma unroll
        for (int q2 = 0; q2 < PSL; ++q2) s += sp[q2][t];
        row[t] = s * inv;
    }
    __syncthreads();
    if (t < HF) {
        float acc = b1[t];
        for (int k = 0; k < HF; ++k) acc = fmaf(row[k], W1[k * HF + t], acc);
        tmp1[g * HF + t] = acc;
        atomicAdd(&bnsum[t], (double)acc);
        atomicAdd(&bnsum[HF + t], (double)(acc * acc));
    }
}

__global__ __launch_bounds__(128) void
head23_kernel(const float* __restrict__ tmp1, const double* __restrict__ bnsum,
              const float* __restrict__ g1, const float* __restrict__ be1,
              const float* __restrict__ W2, const float* __restrict__ b2,
              const float* __restrict__ W3, const float* __restrict__ b3,
              float* __restrict__ out) {
    __shared__ float row[HF], row2[HF];
    int g = blockIdx.x;
    int f = threadIdx.x;
    if (f < HF) {
        double mu = bnsum[f] / (double)NGRAPHS;
        double var = bnsum[HF + f] / (double)NGRAPHS - mu * mu;
        float v = fmaxf((float)var, 0.f) + EPS;
        float a = g1[f] / sqrtf(v);
        float bb = be1[f] - (float)mu * a;
        row[f] = fmaxf(fmaf(tmp1[g * HF + f], a, bb), 0.f);
    }
    __syncthreads();
    if (f < HF) {
        float acc = b2[f];
        for (int k = 0; k < HF; ++k) acc = fmaf(row[k], W2[k * HF + f], acc);
        row2[f] = fmaxf(acc, 0.f);
    }
    __syncthreads();
    if (f < 10) {
        float acc = b3[f];
        for (int k = 0; k < HF; ++k) acc = fmaf(row2[k], W3[k * 10 + f], acc);
        out[g * 10 + f] = acc;
    }
}

// ---------------- launch ----------------

extern "C" void kernel_launch(void* const* d_in, const int* in_sizes, int n_in,
                              void* d_out, int out_size, void* d_ws, size_t ws_size,
                              hipStream_t stream) {
    (void)n_in; (void)out_size; (void)ws_size;
    const float* x     = (const float*)d_in[0];
    const int*   ei    = (const int*)d_in[1];
    const int*   batch = (const int*)d_in[2];
    const float* convW = (const float*)d_in[3];
    const float* convB = (const float*)d_in[4];
    const float* bnG   = (const float*)d_in[5];
    const float* bnB   = (const float*)d_in[6];
    const float* W1    = (const float*)d_in[7];
    const float* b1    = (const float*)d_in[8];
    const float* g1    = (const float*)d_in[9];
    const float* be1   = (const float*)d_in[10];
    const float* W2    = (const float*)d_in[11];
    const float* b2    = (const float*)d_in[12];
    const float* W3    = (const float*)d_in[13];
    const float* b3    = (const float*)d_in[14];
    float* outp = (float*)d_out;

    int N = in_sizes[0] / HF;
    int E = in_sizes[1] / 2;
    int NB = (N + 255) / 256;
    const int* src  = ei;
    const int* dstp = ei + E;

    char* ws = (char*)d_ws;
    size_t off = 0;
    auto alloc = [&](size_t bytes) -> char* {
        char* p = ws + off;
        off += (bytes + 255) & ~(size_t)255;
        return p;
    };
    _Float16* Hb   = (_Float16*)alloc((size_t)N * HF * 2);
    _Float16* Ob   = (_Float16*)alloc((size_t)N * HF * 2);
    int2*  csr     = (int2*)alloc((size_t)E * 8);
    int*   row_ptr = (int*)alloc((size_t)(N + 1) * 4);
    float* dinv    = (float*)alloc((size_t)N * 4);
    float* selfw   = (float*)alloc((size_t)N * 4);
    int*   bsum    = (int*)alloc((size_t)NB * 4);
    int*   boff    = (int*)alloc((size_t)NB * 4);
    float* tmp1    = (float*)alloc((size_t)NGRAPHS * HF * 4);
    _Float16* Wt6  = (_Float16*)alloc((size_t)6 * HF * HF * 2);
    char* zstart   = ws + off;
    int*    cnt    = (int*)alloc((size_t)N * 4);
    double* bns    = (double*)alloc(6 * 2 * HF * 8);   // 5 conv BN + 1 head BN
    size_t zbytes  = (size_t)((ws + off) - zstart);

    hipMemsetAsync(zstart, 0, zbytes, stream);

    wprep_kernel<<<(6 * HF * HF + 255) / 256, 256, 0, stream>>>(convW, Wt6);
    count_kernel<<<1024, 256, 0, stream>>>(dstp, E, cnt);
    scan1_kernel<<<NB, 256, 0, stream>>>(cnt, N, bsum);
    scan2_kernel<<<1, 256, 0, stream>>>(bsum, NB, boff, row_ptr, N);
    scan3_kernel<<<NB, 256, 0, stream>>>(cnt, N, boff, row_ptr, dinv, selfw);
    scatter_kernel<<<1024, 256, 0, stream>>>(src, dstp, E, row_ptr, cnt, dinv, csr);

    int agg_grid = (N * CH + 255) / 256;     // one (node,chunk) item per thread
    int mm_grid = (N + MMROWS - 1) / MMROWS;
    for (int i = 0; i < 6; ++i) {
        matmul_kernel<<<mm_grid, 512, 0, stream>>>(
            (i == 0) ? x : nullptr,
            (i == 0) ? nullptr : (const __half*)Ob,
            Wt6 + (size_t)i * HF * HF, Hb, N,
            (i > 0) ? 1 : 0,
            (i > 0) ? bns + (size_t)(i - 1) * 2 * HF : nullptr,
            (i > 0) ? bnG + (size_t)(i - 1) * HF : nullptr,
            (i > 0) ? bnB + (size_t)(i - 1) * HF : nullptr);
        agg_kernel<<<agg_grid, 256, 0, stream>>>(
            (const __half*)Hb, (__half*)Ob, row_ptr, csr, selfw,
            convB + (size_t)i * HF, N,
            (i < 5) ? bns + (size_t)i * 2 * HF : nullptr);
    }

    pool_head1_kernel<<<NGRAPHS, 256, 0, stream>>>((const __half*)Ob, batch, N,
                                                   W1, b1, tmp1, bns + 5 * 2 * HF);
    head23_kernel<<<NGRAPHS, 128, 0, stream>>>(tmp1, bns + 5 * 2 * HF, g1, be1, W2, b2, W3, b3, outp);
}